// Round 5
// baseline (1520.301 us; speedup 1.0000x reference)
//
#include <hip/hip_runtime.h>

#define NN 50000
#define NE 800000
#define DD 128
#define LN_EPS 1e-5f

typedef __attribute__((ext_vector_type(8))) short v8s;    // 8 bf16
typedef __attribute__((ext_vector_type(4))) unsigned v4u; // same 16B as v8s
typedef __attribute__((ext_vector_type(4))) float f32x4;  // MFMA acc
typedef __attribute__((ext_vector_type(2))) float f32x2;  // packed-f32 pair

union CvtHL { v4u u; v8s s; };

__device__ __forceinline__ float leakyf(float x){ return x > 0.f ? x : 0.05f*x; }
__device__ __forceinline__ short f2bf(float f){
  unsigned u = __float_as_uint(f);
  u = (u + 0x7fffu + ((u >> 16) & 1u)) >> 16;   // RNE
  return (short)u;
}
__device__ __forceinline__ float bf2f(unsigned short h){
  return __uint_as_float(((unsigned)h) << 16);
}
// HW RNE pack: low16 = bf16(a), high16 = bf16(b). 1 inst for 2 values.
__device__ __forceinline__ unsigned cvt_pk_bf16(float a, float b){
  unsigned r;
  asm("v_cvt_pk_bf16_f32 %0, %1, %2" : "=v"(r) : "v"(a), "v"(b));
  return r;
}
// packed f32 math (CDNA VOP3P): 2 floats / instruction
__device__ __forceinline__ f32x2 pk_add(f32x2 a, f32x2 b){
  f32x2 r; asm("v_pk_add_f32 %0, %1, %2" : "=v"(r) : "v"(a), "v"(b)); return r;
}
__device__ __forceinline__ f32x2 pk_mul(f32x2 a, f32x2 b){
  f32x2 r; asm("v_pk_mul_f32 %0, %1, %2" : "=v"(r) : "v"(a), "v"(b)); return r;
}
// [hi16(u0) | hi16(u1)<<16] in one v_perm_b32
__device__ __forceinline__ unsigned pack_hi16(unsigned u0, unsigned u1){
  return __builtin_amdgcn_perm(u1, u0, 0x07060302u);
}
// split fp32 -> {hi, lo}: hi = truncated top-16 (cheap), lo = RNE(residual).
__device__ __forceinline__ short2 f2bf2v(float v){
  unsigned u = __float_as_uint(v);
  short hi = (short)(u >> 16);
  float lo = v - __uint_as_float(u & 0xffff0000u);
  return make_short2(hi, f2bf(lo));
}

// ---------------------------------------------------------------------------
// Weight packing. Layout: [(k>>3)*128+n][k&7] hi/lo bf16 planes.
// pack_small: y=0 node-encoder W1 (K=19 padded to 32) -> hi/lo planes;
//             y=1 edge-encoder W1+b1 folded single plane (see below).
// ---------------------------------------------------------------------------
__global__ void pack_small_kernel(const float* __restrict__ nW1,
                                  short* __restrict__ nWh, short* __restrict__ nWl,
                                  const float* __restrict__ eW1, const float* __restrict__ eb1,
                                  short* __restrict__ eWp)
{
  int idx = blockIdx.x*256 + threadIdx.x;   // 0..4095
  int k = idx >> 7, n = idx & 127;
  size_t o = ((size_t)(k >> 3)*128 + n)*8 + (k & 7);
  if (blockIdx.y == 0) {
    float v = (k < 19) ? nW1[k*128 + n] : 0.f;
    short2 t = f2bf2v(v);
    nWh[o] = t.x; nWl[o] = t.y;
  } else {
    // rows 0-3: hi(W1) (pairs A=xh); 4-7: lo(W1) (A=xh); 8-11: hi(W1) (A=xl);
    // 12: hi(b1), 13: lo(b1) (A=1.0); rest 0. One MFMA = xh@Wh+xh@Wl+xl@Wh+b1.
    short v = 0;
    if (k < 4)        v = f2bf2v(eW1[k*128 + n]).x;
    else if (k < 8)   v = f2bf2v(eW1[(k-4)*128 + n]).y;
    else if (k < 12)  v = f2bf2v(eW1[(k-8)*128 + n]).x;
    else if (k == 12) v = f2bf2v(eb1[n]).x;
    else if (k == 13) v = f2bf2v(eb1[n]).y;
    eWp[o] = v;
  }
}

#define NPACK 12
struct PackArgs { const float* src[NPACK]; short* dh[NPACK]; short* dl[NPACK]; };

// all-K=128 batch pack: grid (64, NPACK)
__global__ void pack_many_kernel(PackArgs pa)
{
  int m = blockIdx.y;
  int idx = blockIdx.x*256 + threadIdx.x;   // 0..16383
  int k = idx >> 7, n = idx & 127;
  float v = pa.src[m][k*128 + n];
  short2 t = f2bf2v(v);
  size_t o = ((size_t)(k >> 3)*128 + n)*8 + (k & 7);
  pa.dh[m][o] = t.x; pa.dl[m][o] = t.y;
}

// full split-split product (A has hi+lo)
#define MFMA3(ah, al, bh, bl, ac) \
  ac = __builtin_amdgcn_mfma_f32_16x16x32_bf16(al, bh, ac, 0,0,0); \
  ac = __builtin_amdgcn_mfma_f32_16x16x32_bf16(ah, bl, ac, 0,0,0); \
  ac = __builtin_amdgcn_mfma_f32_16x16x32_bf16(ah, bh, ac, 0,0,0);

// A exact-bf16 (no lo plane): 2 MFMAs
#define MFMA2(ah, bh, bl, ac) \
  ac = __builtin_amdgcn_mfma_f32_16x16x32_bf16(ah, bl, ac, 0,0,0); \
  ac = __builtin_amdgcn_mfma_f32_16x16x32_bf16(ah, bh, ac, 0,0,0);

// 8 fp32 -> hi-plane (v_perm pack) + lo-plane (cvt_pk RNE)
#define SPLIT8(f0, f1, h, l) { \
  unsigned u0=__float_as_uint(f0.x), u1=__float_as_uint(f0.y), u2=__float_as_uint(f0.z), u3=__float_as_uint(f0.w); \
  unsigned u4=__float_as_uint(f1.x), u5=__float_as_uint(f1.y), u6=__float_as_uint(f1.z), u7=__float_as_uint(f1.w); \
  CvtHL ch_, cl_; \
  ch_.u = (v4u){ pack_hi16(u0,u1), pack_hi16(u2,u3), pack_hi16(u4,u5), pack_hi16(u6,u7) }; \
  cl_.u = (v4u){ \
    cvt_pk_bf16(f0.x-__uint_as_float(u0&0xffff0000u), f0.y-__uint_as_float(u1&0xffff0000u)), \
    cvt_pk_bf16(f0.z-__uint_as_float(u2&0xffff0000u), f0.w-__uint_as_float(u3&0xffff0000u)), \
    cvt_pk_bf16(f1.x-__uint_as_float(u4&0xffff0000u), f1.y-__uint_as_float(u5&0xffff0000u)), \
    cvt_pk_bf16(f1.z-__uint_as_float(u6&0xffff0000u), f1.w-__uint_as_float(u7&0xffff0000u)) }; \
  h = ch_.s; l = cl_.s; }

// bias + leaky + bf16-pack on paired acc halves. Bit-identical to the scalar
// version: x=acc+bv (pk_add), m=0.05*x (pk_mul), max, HW-RNE cvt.
#define EPI_PK(accv, bv2, DOBIAS, p01, p23) { \
  f32x2 x01 = (f32x2){(accv)[0], (accv)[1]}; \
  f32x2 x23 = (f32x2){(accv)[2], (accv)[3]}; \
  if (DOBIAS) { x01 = pk_add(x01, bv2); x23 = pk_add(x23, bv2); } \
  f32x2 m01 = pk_mul(x01, (f32x2)(0.05f)); \
  f32x2 m23 = pk_mul(x23, (f32x2)(0.05f)); \
  p01 = cvt_pk_bf16(fmaxf(x01.x, m01.x), fmaxf(x01.y, m01.y)); \
  p23 = cvt_pk_bf16(fmaxf(x23.x, m23.x), fmaxf(x23.y, m23.y)); }

// ---------------------------------------------------------------------------
// 3-layer MLP + LayerNorm. Layer-1 inputs and all weights hi/lo split;
// hidden activations single-bf16 (layers 2/3 use 2 MFMAs).
// SCATTER (edge): layer-1 uses the single-plane combined weight (1 MFMA/tile,
// bias folded into K); LN stats use a shared reduce-scatter butterfly;
// seg-reduce flushes are pre-scaled by invcnt[src] and land directly in hn
// (scatter-MEAN fused -> no esum buffer / memset / addmean pass).
// ---------------------------------------------------------------------------
template<int IN_W, bool SCATTER>
__global__ __launch_bounds__(256)
void mlp_mfma_kernel(const float* __restrict__ x, int nrows,
                     const short* __restrict__ W1h, const short* __restrict__ W1l,
                     const float* __restrict__ b1,
                     const short* __restrict__ W2h, const short* __restrict__ W2l,
                     const float* __restrict__ b2,
                     const short* __restrict__ W3h, const short* __restrict__ W3l,
                     const float* __restrict__ b3,
                     const float* __restrict__ g, const float* __restrict__ bb,
                     float* __restrict__ out,
                     const int* __restrict__ sidx,   // src-sorted src values
                     const int* __restrict__ eperm,  // sorted pos -> edge id
                     const float* __restrict__ invcnt) // 1/max(cnt,1) per node
{
  constexpr int L1K = (IN_W + 31) / 32;
  constexpr bool EDGE1 = (SCATTER && IN_W == 4);
  __shared__ __align__(16) short Hh[128*136];   // act plane; reused (stride 132) as bf16 seg buffer
  __shared__ float lnS[128][2], lnQ[128][2];
  __shared__ int sidx_s[128];
  __shared__ __align__(16) uint4 xstage[SCATTER ? 128 : 1];  // pre-split hi/lo packs

  const int tid  = threadIdx.x;
  const int lane = tid & 63, wave = tid >> 6;
  const int wr = wave >> 1, wc = wave & 1;
  const int quad = lane >> 4, low = lane & 15;
  const int row0 = blockIdx.x * 128;

  if (SCATTER) {
    // 128 parallel scattered gathers + hi/lo split -> LDS stage
    if (tid < 128) {
      int e = eperm[row0 + tid];           // NE % 128 == 0
      float4 f = ((const float4*)x)[e];
      unsigned u0=__float_as_uint(f.x), u1=__float_as_uint(f.y);
      unsigned u2=__float_as_uint(f.z), u3=__float_as_uint(f.w);
      uint4 st;
      st.x = pack_hi16(u0,u1);
      st.y = pack_hi16(u2,u3);
      st.z = cvt_pk_bf16(f.x-__uint_as_float(u0&0xffff0000u), f.y-__uint_as_float(u1&0xffff0000u));
      st.w = cvt_pk_bf16(f.z-__uint_as_float(u2&0xffff0000u), f.w-__uint_as_float(u3&0xffff0000u));
      xstage[tid] = st;
      sidx_s[tid] = sidx[row0 + tid];
    }
    __syncthreads();
  }

  f32x4 acc[4][4];

  // ---------------- layer 1 ----------------
  #pragma unroll
  for (int tm=0;tm<4;tm++)
    #pragma unroll
    for (int tn=0;tn<4;tn++) acc[tm][tn] = (f32x4)0.f;

  if constexpr (EDGE1) {
    // single-plane: K slots 0-7 = xh (pairs Wh,Wl rows), 8-11 = xl (pairs Wh),
    // 12-13 = 1.0 (pairs b1 hi/lo rows). One MFMA per tile.
    v8s ah[4], bh[4];
    #pragma unroll
    for (int tm=0;tm<4;tm++) {
      int lr = wr*64 + tm*16 + low;
      v8s h = (v8s)0;
      if (quad == 0) {
        uint4 st = xstage[lr];
        CvtHL c_; c_.u = (v4u){ st.x, st.y, st.x, st.y };
        h = c_.s;
      } else if (quad == 1) {
        uint4 st = xstage[lr];
        CvtHL c_; c_.u = (v4u){ st.z, st.w, 0x3F803F80u, 0u };
        h = c_.s;
      }
      ah[tm] = h;
    }
    #pragma unroll
    for (int tn=0;tn<4;tn++) {
      size_t o = ((size_t)quad*128 + wc*64 + tn*16 + low)*8;
      bh[tn] = *(const v8s*)(W1h + o);
    }
    #pragma unroll
    for (int tm=0;tm<4;tm++)
      #pragma unroll
      for (int tn=0;tn<4;tn++)
        acc[tm][tn] = __builtin_amdgcn_mfma_f32_16x16x32_bf16(ah[tm], bh[tn], acc[tm][tn], 0,0,0);
  } else {
    for (int ks = 0; ks < L1K; ks++) {
      v8s ah[4], al[4], bh[4], bl[4];
      #pragma unroll
      for (int tm=0;tm<4;tm++) {
        int lr = wr*64 + tm*16 + low;
        v8s h = (v8s)0, l = (v8s)0;
        if (IN_W % 32 == 0) {
          int r = row0 + lr;
          if (r < nrows) {
            const float* p = x + (size_t)r*IN_W + ks*32 + quad*8;
            float4 f0 = *(const float4*)p;
            float4 f1 = *(const float4*)(p + 4);
            SPLIT8(f0, f1, h, l);
          }
        } else {
          int r = row0 + lr;
          #pragma unroll
          for (int j=0;j<8;j++) {
            int k = ks*32 + quad*8 + j;
            if (k < IN_W && r < nrows) {
              short2 t = f2bf2v(x[(size_t)r*IN_W + k]);
              h[j] = t.x; l[j] = t.y;
            }
          }
        }
        ah[tm] = h; al[tm] = l;
      }
      #pragma unroll
      for (int tn=0;tn<4;tn++) {
        size_t o = ((size_t)(ks*4+quad)*128 + wc*64 + tn*16 + low)*8;
        bh[tn] = *(const v8s*)(W1h + o);
        bl[tn] = *(const v8s*)(W1l + o);
      }
      #pragma unroll
      for (int tm=0;tm<4;tm++)
        #pragma unroll
        for (int tn=0;tn<4;tn++) { MFMA3(ah[tm], al[tm], bh[tn], bl[tn], acc[tm][tn]); }
    }
  }
  #pragma unroll
  for (int tn=0;tn<4;tn++) {
    float bv = EDGE1 ? 0.f : b1[wc*64 + tn*16 + low];
    f32x2 bv2 = (f32x2)(bv);
    #pragma unroll
    for (int tm=0;tm<4;tm++) {
      unsigned p01, p23;
      EPI_PK(acc[tm][tn], bv2, !EDGE1, p01, p23);
      int base = (wr*64+tm*16+quad*4)*136 + wc*64+tn*16+low;
      Hh[base]     = (short)p01;
      Hh[base+136] = (short)(p01>>16);
      Hh[base+272] = (short)p23;
      Hh[base+408] = (short)(p23>>16);
    }
  }
  __syncthreads();

  // ---------------- layer 2 (bf16 A from LDS, 2 MFMAs) ----------------
  #pragma unroll
  for (int tm=0;tm<4;tm++)
    #pragma unroll
    for (int tn=0;tn<4;tn++) acc[tm][tn] = (f32x4)0.f;
  #pragma unroll
  for (int ks=0;ks<4;ks++) {
    v8s ah[4], bh[4], bl[4];
    #pragma unroll
    for (int tm=0;tm<4;tm++)
      ah[tm] = *(const v8s*)&Hh[(wr*64+tm*16+low)*136 + ks*32 + quad*8];
    #pragma unroll
    for (int tn=0;tn<4;tn++) {
      size_t o = ((size_t)(ks*4+quad)*128 + wc*64 + tn*16 + low)*8;
      bh[tn] = *(const v8s*)(W2h + o);
      bl[tn] = *(const v8s*)(W2l + o);
    }
    #pragma unroll
    for (int tm=0;tm<4;tm++)
      #pragma unroll
      for (int tn=0;tn<4;tn++) { MFMA2(ah[tm], bh[tn], bl[tn], acc[tm][tn]); }
  }
  __syncthreads();
  #pragma unroll
  for (int tn=0;tn<4;tn++) {
    float bv = b2[wc*64 + tn*16 + low];
    f32x2 bv2 = (f32x2)(bv);
    #pragma unroll
    for (int tm=0;tm<4;tm++) {
      unsigned p01, p23;
      EPI_PK(acc[tm][tn], bv2, true, p01, p23);
      int base = (wr*64+tm*16+quad*4)*136 + wc*64+tn*16+low;
      Hh[base]     = (short)p01;
      Hh[base+136] = (short)(p01>>16);
      Hh[base+272] = (short)p23;
      Hh[base+408] = (short)(p23>>16);
    }
  }
  __syncthreads();

  // ---------------- layer 3 (bf16 A from LDS, 2 MFMAs) ----------------
  #pragma unroll
  for (int tm=0;tm<4;tm++)
    #pragma unroll
    for (int tn=0;tn<4;tn++) acc[tm][tn] = (f32x4)0.f;
  #pragma unroll
  for (int ks=0;ks<4;ks++) {
    v8s ah[4], bh[4], bl[4];
    #pragma unroll
    for (int tm=0;tm<4;tm++)
      ah[tm] = *(const v8s*)&Hh[(wr*64+tm*16+low)*136 + ks*32 + quad*8];
    #pragma unroll
    for (int tn=0;tn<4;tn++) {
      size_t o = ((size_t)(ks*4+quad)*128 + wc*64 + tn*16 + low)*8;
      bh[tn] = *(const v8s*)(W3h + o);
      bl[tn] = *(const v8s*)(W3l + o);
    }
    #pragma unroll
    for (int tm=0;tm<4;tm++)
      #pragma unroll
      for (int tn=0;tn<4;tn++) { MFMA2(ah[tm], bh[tn], bl[tn], acc[tm][tn]); }
  }
  #pragma unroll
  for (int tn=0;tn<4;tn++) {
    float bv = b3[wc*64 + tn*16 + low];
    #pragma unroll
    for (int tm=0;tm<4;tm++)
      #pragma unroll
      for (int i=0;i<4;i++) acc[tm][tn][i] += bv;
  }

  // ---------------- fused LayerNorm ----------------
  // Reduce-scatter butterfly: all 16 (tm,i) row-reductions share one 4-step
  // butterfly (masks 1,2,4,8 — identical tree association, bit-identical).
  {
    float ct[16];
    #pragma unroll
    for (int tm=0;tm<4;tm++)
      #pragma unroll
      for (int i=0;i<4;i++)
        ct[tm*4+i] = acc[tm][0][i] + acc[tm][1][i] + acc[tm][2][i] + acc[tm][3][i];
    #pragma unroll
    for (int st=0; st<4; st++) {
      const int mm = 1 << st;
      const bool hbit = ((low >> st) & 1) != 0;
      #pragma unroll
      for (int p=0; p < (16>>st); p+=2) {
        float snd = hbit ? ct[p]   : ct[p+1];
        float kp  = hbit ? ct[p+1] : ct[p];
        ct[p>>1] = kp + __shfl_xor(snd, mm);
      }
    }
    { int r = wr*64 + (low>>2)*16 + quad*4 + (low&3); lnS[r][wc] = ct[0]; }
    #pragma unroll
    for (int tm=0;tm<4;tm++)
      #pragma unroll
      for (int i=0;i<4;i++)
        ct[tm*4+i] = acc[tm][0][i]*acc[tm][0][i] + acc[tm][1][i]*acc[tm][1][i]
                   + acc[tm][2][i]*acc[tm][2][i] + acc[tm][3][i]*acc[tm][3][i];
    #pragma unroll
    for (int st=0; st<4; st++) {
      const int mm = 1 << st;
      const bool hbit = ((low >> st) & 1) != 0;
      #pragma unroll
      for (int p=0; p < (16>>st); p+=2) {
        float snd = hbit ? ct[p]   : ct[p+1];
        float kp  = hbit ? ct[p+1] : ct[p];
        ct[p>>1] = kp + __shfl_xor(snd, mm);
      }
    }
    { int r = wr*64 + (low>>2)*16 + quad*4 + (low&3); lnQ[r][wc] = ct[0]; }
  }
  __syncthreads();   // all layer-3 H reads done (act-plane reuse below is safe)

  float g4[4], bb4[4];
  #pragma unroll
  for (int tn=0;tn<4;tn++) { int c = wc*64+tn*16+low; g4[tn] = g[c]; bb4[tn] = bb[c]; }

  #pragma unroll
  for (int tm=0;tm<4;tm++)
    #pragma unroll
    for (int i=0;i<4;i++) {
      int r = wr*64 + tm*16 + quad*4 + i;
      float2 S2 = *(const float2*)&lnS[r][0];
      float2 Q2 = *(const float2*)&lnQ[r][0];
      float s = S2.x + S2.y;
      float q = Q2.x + Q2.y;
      float m = s * (1.f/128.f);
      float var = q * (1.f/128.f) - m*m;
      float rs = rsqrtf(var + LN_EPS);
      int gr = row0 + r;
      if (!SCATTER && gr >= nrows) continue;
      float v0 = (acc[tm][0][i] - m) * rs * g4[0] + bb4[0];
      float v1 = (acc[tm][1][i] - m) * rs * g4[1] + bb4[1];
      float v2 = (acc[tm][2][i] - m) * rs * g4[2] + bb4[2];
      float v3 = (acc[tm][3][i] - m) * rs * g4[3] + bb4[3];
      if (SCATTER) {
        unsigned p01 = cvt_pk_bf16(v0, v1), p23 = cvt_pk_bf16(v2, v3);
        int base = r*132 + wc*64 + low;
        Hh[base]    = (short)p01;      // bf16 stage for seg-reduce
        Hh[base+16] = (short)(p01>>16);
        Hh[base+32] = (short)p23;
        Hh[base+48] = (short)(p23>>16);
      } else {
        size_t ob = (size_t)gr*DD + wc*64 + low;
        out[ob]    = v0;
        out[ob+16] = v1;
        out[ob+32] = v2;
        out[ob+48] = v3;
      }
    }

  if (SCATTER) {
    __syncthreads();
    // dword-vectorized seg-reduce: wave g handles rows [g*32, g*32+32),
    // 64 col-pairs; flushes scaled by invcnt[cur] straight into hn.
    const unsigned* H32 = (const unsigned*)Hh;    // row stride 66 dwords
    int cp = tid & 63;
    int gI = tid >> 6;
    int rbeg = gI*32, rend = rbeg + 32;
    unsigned pv = H32[rbeg*66 + cp];
    float a0 = __uint_as_float(pv << 16), a1 = __uint_as_float(pv & 0xffff0000u);
    int cur = __builtin_amdgcn_readfirstlane(sidx_s[rbeg]);
    for (int r = rbeg + 1; r < rend; r++) {
      int sv = __builtin_amdgcn_readfirstlane(sidx_s[r]);   // wave-uniform scalar
      unsigned hv = H32[r*66 + cp];
      if (sv != cur) {
        float ic = invcnt[cur];
        atomicAdd(&out[(size_t)cur*DD + 2*cp],     a0*ic);
        atomicAdd(&out[(size_t)cur*DD + 2*cp + 1], a1*ic);
        a0 = __uint_as_float(hv << 16); a1 = __uint_as_float(hv & 0xffff0000u);
        cur = sv;
      } else {
        a0 += __uint_as_float(hv << 16); a1 += __uint_as_float(hv & 0xffff0000u);
      }
    }
    float ic = invcnt[cur];
    atomicAdd(&out[(size_t)cur*DD + 2*cp],     a0*ic);
    atomicAdd(&out[(size_t)cur*DD + 2*cp + 1], a1*ic);
  }
}

// ---------------------------------------------------------------------------
// outbf[r] = bf16((x[r] @ W + initv) * rowscale[r])  — fp32 input (split, 3 MFMA)
// ---------------------------------------------------------------------------
__global__ __launch_bounds__(256)
void gemm_mfma_kernel(const float* __restrict__ x,
                      const short* __restrict__ Wh, const short* __restrict__ Wl,
                      const float* __restrict__ initv, const float* __restrict__ rowscale,
                      unsigned short* __restrict__ outbf, int nrows)
{
  const int tid  = threadIdx.x;
  const int lane = tid & 63, wave = tid >> 6;
  const int wr = wave >> 1, wc = wave & 1;
  const int quad = lane >> 4, low = lane & 15;
  const int row0 = blockIdx.x * 64;

  f32x4 acc[2][4];
  #pragma unroll
  for (int tm=0;tm<2;tm++)
    #pragma unroll
    for (int tn=0;tn<4;tn++) acc[tm][tn] = (f32x4)0.f;

  #pragma unroll
  for (int ks=0;ks<4;ks++) {
    v8s ah[2], al[2], bh[4], bl[4];
    #pragma unroll
    for (int tm=0;tm<2;tm++) {
      int r = row0 + wr*32 + tm*16 + low;
      v8s h = (v8s)0, l = (v8s)0;
      if (r < nrows) {
        const float* p = x + (size_t)r*DD + ks*32 + quad*8;
        float4 f0 = *(const float4*)p;
        float4 f1 = *(const float4*)(p + 4);
        SPLIT8(f0, f1, h, l);
      }
      ah[tm] = h; al[tm] = l;
    }
    #pragma unroll
    for (int tn=0;tn<4;tn++) {
      size_t o = ((size_t)(ks*4+quad)*128 + wc*64 + tn*16 + low)*8;
      bh[tn] = *(const v8s*)(Wh + o);
      bl[tn] = *(const v8s*)(Wl + o);
    }
    #pragma unroll
    for (int tm=0;tm<2;tm++)
      #pragma unroll
      for (int tn=0;tn<4;tn++) { MFMA3(ah[tm], al[tm], bh[tn], bl[tn], acc[tm][tn]); }
  }

  float iv4[4];
  #pragma unroll
  for (int tn=0;tn<4;tn++) iv4[tn] = initv ? initv[wc*64 + tn*16 + low] : 0.f;

  #pragma unroll
  for (int tm=0;tm<2;tm++)
    #pragma unroll
    for (int i=0;i<4;i++) {
      int gr = row0 + wr*32 + tm*16 + quad*4 + i;
      if (gr >= nrows) continue;
      float sc = rowscale ? rowscale[gr] : 1.f;
      float v0 = (acc[tm][0][i] + iv4[0]) * sc;
      float v1 = (acc[tm][1][i] + iv4[1]) * sc;
      float v2 = (acc[tm][2][i] + iv4[2]) * sc;
      float v3 = (acc[tm][3][i] + iv4[3]) * sc;
      unsigned p01 = cvt_pk_bf16(v0, v1), p23 = cvt_pk_bf16(v2, v3);
      size_t base = (size_t)gr*DD + wc*64 + low;
      outbf[base]    = (unsigned short)p01;
      outbf[base+16] = (unsigned short)(p01>>16);
      outbf[base+32] = (unsigned short)p23;
      outbf[base+48] = (unsigned short)(p23>>16);
    }
}

// ---------------------------------------------------------------------------
// Same but bf16 input (exact, 2 MFMA, 16 B/lane A-loads) — conv2 on y.
// ---------------------------------------------------------------------------
__global__ __launch_bounds__(256)
void gemm_bf_mfma_kernel(const unsigned short* __restrict__ xb,
                         const short* __restrict__ Wh, const short* __restrict__ Wl,
                         const float* __restrict__ initv, const float* __restrict__ rowscale,
                         unsigned short* __restrict__ outbf, int nrows)
{
  const int tid  = threadIdx.x;
  const int lane = tid & 63, wave = tid >> 6;
  const int wr = wave >> 1, wc = wave & 1;
  const int quad = lane >> 4, low = lane & 15;
  const int row0 = blockIdx.x * 64;

  f32x4 acc[2][4];
  #pragma unroll
  for (int tm=0;tm<2;tm++)
    #pragma unroll
    for (int tn=0;tn<4;tn++) acc[tm][tn] = (f32x4)0.f;

  #pragma unroll
  for (int ks=0;ks<4;ks++) {
    v8s ah[2], bh[4], bl[4];
    #pragma unroll
    for (int tm=0;tm<2;tm++) {
      int r = row0 + wr*32 + tm*16 + low;
      ah[tm] = (r < nrows) ? *(const v8s*)(xb + (size_t)r*DD + ks*32 + quad*8) : (v8s)0;
    }
    #pragma unroll
    for (int tn=0;tn<4;tn++) {
      size_t o = ((size_t)(ks*4+quad)*128 + wc*64 + tn*16 + low)*8;
      bh[tn] = *(const v8s*)(Wh + o);
      bl[tn] = *(const v8s*)(Wl + o);
    }
    #pragma unroll
    for (int tm=0;tm<2;tm++)
      #pragma unroll
      for (int tn=0;tn<4;tn++) { MFMA2(ah[tm], bh[tn], bl[tn], acc[tm][tn]); }
  }

  float iv4[4];
  #pragma unroll
  for (int tn=0;tn<4;tn++) iv4[tn] = initv ? initv[wc*64 + tn*16 + low] : 0.f;

  #pragma unroll
  for (int tm=0;tm<2;tm++)
    #pragma unroll
    for (int i=0;i<4;i++) {
      int gr = row0 + wr*32 + tm*16 + quad*4 + i;
      if (gr >= nrows) continue;
      float sc = rowscale ? rowscale[gr] : 1.f;
      float v0 = (acc[tm][0][i] + iv4[0]) * sc;
      float v1 = (acc[tm][1][i] + iv4[1]) * sc;
      float v2 = (acc[tm][2][i] + iv4[2]) * sc;
      float v3 = (acc[tm][3][i] + iv4[3]) * sc;
      unsigned p01 = cvt_pk_bf16(v0, v1), p23 = cvt_pk_bf16(v2, v3);
      size_t base = (size_t)gr*DD + wc*64 + low;
      outbf[base]    = (unsigned short)p01;
      outbf[base+16] = (unsigned short)(p01>>16);
      outbf[base+32] = (unsigned short)p23;
      outbf[base+48] = (unsigned short)(p23>>16);
    }
}

// ---------------------------------------------------------------------------
// GCN aggregation, COLUMN-SLICED for per-XCD L2 residency.
// Grid (NN/16, 4): blockIdx.y = slice of 32 cols (16 dwords = 64 B/row).
// Per-phase table slice = 3.2 MB < 4 MiB per-XCD L2 (vs 12.8 MB full table),
// and x-fastest dispatch order keeps phases temporally separated.
// Each 16-lane quad owns one node's slice chunk; CSR walk + 16/4/1 unroll +
// per-lane (per-column) accumulation order identical to the R1-proven kernel
// -> bit-identical results, same 16 loads-in-flight per lane.
// mode 0: outb = bf16(leaky(agg))   mode 1: outf = resid + agg (fp32)
// ---------------------------------------------------------------------------
__global__ __launch_bounds__(256)
void gcn_agg_kernel(const unsigned* __restrict__ hb, const int* __restrict__ rowptr,
                    const int* __restrict__ csr_src, const float* __restrict__ dis,
                    const float* __restrict__ bias, const float* __restrict__ resid,
                    float* __restrict__ outf, unsigned* __restrict__ outb, int mode)
{
  const int lane = threadIdx.x & 63;
  const int wv   = threadIdx.x >> 6;
  const int q    = lane >> 4;                    // node-within-wave (quad)
  const int c    = lane & 15;                    // dword within 64B slice chunk
  const int soff = blockIdx.y * 16 + c;          // dword offset in 64-dword row
  const int i    = blockIdx.x * 16 + wv * 4 + q; // node (NN % 16 == 0)

  unsigned hv = hb[(size_t)i * 64 + soff];       // self term
  float ax = bf2f((unsigned short)(hv & 0xffff));
  float ay = bf2f((unsigned short)(hv >> 16));
  const int beg = rowptr[i], end = rowptr[i + 1];
  int j = beg;
  for (; j + 16 <= end; j += 16) {
    unsigned v[16];
    #pragma unroll
    for (int k = 0; k < 16; k++) v[k] = hb[(size_t)csr_src[j + k] * 64 + soff];
    #pragma unroll
    for (int k = 0; k < 16; k++) {
      ax += bf2f((unsigned short)(v[k] & 0xffff));
      ay += bf2f((unsigned short)(v[k] >> 16));
    }
  }
  for (; j + 4 <= end; j += 4) {
    unsigned v[4];
    #pragma unroll
    for (int k = 0; k < 4; k++) v[k] = hb[(size_t)csr_src[j + k] * 64 + soff];
    #pragma unroll
    for (int k = 0; k < 4; k++) {
      ax += bf2f((unsigned short)(v[k] & 0xffff));
      ay += bf2f((unsigned short)(v[k] >> 16));
    }
  }
  for (; j < end; j++) {
    unsigned v = hb[(size_t)csr_src[j] * 64 + soff];
    ax += bf2f((unsigned short)(v & 0xffff));
    ay += bf2f((unsigned short)(v >> 16));
  }
  float di = dis[i];
  float2 bv = ((const float2*)bias)[soff];
  ax = ax * di + bv.x; ay = ay * di + bv.y;
  size_t o = (size_t)i * 64 + soff;
  if (mode == 0) {
    outb[o] = cvt_pk_bf16(leakyf(ax), leakyf(ay));
  } else {
    float2 rs = ((const float2*)resid)[o];
    float2 r; r.x = rs.x + ax; r.y = rs.y + ay;
    ((float2*)outf)[o] = r;
  }
}

// ---------------------------------------------------------------------------
// Graph setup
// ---------------------------------------------------------------------------
__global__ void count_kernel(const int* __restrict__ src, const int* __restrict__ dst,
                             int* __restrict__ cnt_src, int* __restrict__ deg_dst)
{
  int e = blockIdx.x*blockDim.x + threadIdx.x;
  if (e < NE) {
    atomicAdd(&cnt_src[src[e]], 1);
    atomicAdd(&deg_dst[dst[e]], 1);
  }
}

// two independent single-block scans; also folds nodeparams:
// block 0: deg -> rowptr,nextp + dis = rsqrt(deg+1)
// block 1: cnt -> srow,nexts   + invcnt = 1/max(cnt,1)
__global__ void scan2_kernel(const int* __restrict__ a0, int* __restrict__ r0, int* __restrict__ n0,
                             float* __restrict__ aux0,
                             const int* __restrict__ a1, int* __restrict__ r1, int* __restrict__ n1,
                             float* __restrict__ aux1)
{
  const int* a = blockIdx.x ? a1 : a0;
  int* r = blockIdx.x ? r1 : r0;
  int* n = blockIdx.x ? n1 : n0;
  float* aux = blockIdx.x ? aux1 : aux0;
  const int T = 256;
  int tid = threadIdx.x;
  int chunk = (NN + T - 1) / T;
  int begin = tid*chunk, end = begin + chunk; if (end > NN) end = NN; if (begin > NN) begin = NN;
  int s = 0;
  for (int i = begin; i < end; i++) s += a[i];
  __shared__ int ps[T];
  ps[tid] = s; __syncthreads();
  for (int off = 1; off < T; off <<= 1) {
    int v = 0;
    if (tid >= off) v = ps[tid - off];
    __syncthreads();
    if (tid >= off) ps[tid] += v;
    __syncthreads();
  }
  int base = (tid == 0) ? 0 : ps[tid-1];
  for (int i = begin; i < end; i++) {
    r[i] = base; n[i] = base; base += a[i];
    aux[i] = blockIdx.x ? (1.0f / fmaxf((float)a[i], 1.0f)) : rsqrtf((float)a[i] + 1.0f);
  }
  if (tid == T-1) r[NN] = base;
}

// fused CSR fill + src-sort fill (one pass over the edge list)
__global__ void fill_both_kernel(const int* __restrict__ src, const int* __restrict__ dst,
                                 int* __restrict__ nextp, int* __restrict__ csr_src,
                                 int* __restrict__ nexts, int* __restrict__ eperm,
                                 int* __restrict__ srcsorted)
{
  int e = blockIdx.x*blockDim.x + threadIdx.x;
  if (e < NE) {
    int s = src[e];
    int pos = atomicAdd(&nextp[dst[e]], 1);
    csr_src[pos] = s;
    int ps = atomicAdd(&nexts[s], 1);
    eperm[ps] = e;
    srcsorted[ps] = s;
  }
}

// ---------------------------------------------------------------------------
// BatchNorm stats (bf16 y) — dword loads (2 cols/thread), 4-row groups.
// ---------------------------------------------------------------------------
__global__ __launch_bounds__(256)
void bn_stats_kernel(const unsigned* __restrict__ yb32, float* __restrict__ sums)
{
  int cp  = threadIdx.x & 63;   // col pair 0..63
  int grp = threadIdx.x >> 6;   // 0..3
  float s0=0.f, s1=0.f, q0=0.f, q1=0.f;
  for (int i = blockIdx.x*4 + grp; i < NN; i += gridDim.x*4) {
    unsigned v = yb32[(size_t)i*64 + cp];
    float a = __uint_as_float(v << 16);
    float b = __uint_as_float(v & 0xffff0000u);
    s0 += a; q0 += a*a; s1 += b; q1 += b*b;
  }
  __shared__ float red[256][4];
  red[threadIdx.x][0]=s0; red[threadIdx.x][1]=s1; red[threadIdx.x][2]=q0; red[threadIdx.x][3]=q1;
  __syncthreads();
  if (grp == 0) {
    float t0=0.f,t1=0.f,t2=0.f,t3=0.f;
    #pragma unroll
    for (int g2=0; g2<4; g2++) {
      t0+=red[g2*64+cp][0]; t1+=red[g2*64+cp][1]; t2+=red[g2*64+cp][2]; t3+=red[g2*64+cp][3];
    }
    atomicAdd(&sums[2*cp],      t0);
    atomicAdd(&sums[2*cp+1],    t1);
    atomicAdd(&sums[DD+2*cp],   t2);
    atomicAdd(&sums[DD+2*cp+1], t3);
  }
}

// grid = 16 blocks; block b handles k in [b*8, b*8+8). cvec pre-zeroed.
__global__ __launch_bounds__(256)
void bn_fold_kernel(const float* __restrict__ sums, const float* __restrict__ g,
                    const float* __restrict__ b, const float* __restrict__ W2,
                    short* __restrict__ Wfh, short* __restrict__ Wfl,
                    float* __restrict__ cvec)
{
  __shared__ float scale_s[DD], shift_s[DD];
  int tid = threadIdx.x;
  if (tid < DD) {
    float m = sums[tid] / (float)NN;
    float var = sums[DD + tid] / (float)NN - m*m;
    float is = rsqrtf(var + LN_EPS);
    float sc = is * g[tid];
    scale_s[tid] = sc;
    shift_s[tid] = b[tid] - m * sc;
  }
  __syncthreads();
  int col = tid & 127, kh = tid >> 7;   // kh = 0..1
  float cpart = 0.f;
  #pragma unroll
  for (int kk = 0; kk < 4; kk++) {
    int k = blockIdx.x*8 + kh*4 + kk;
    float w = W2[k*DD + col];
    short2 t = f2bf2v(w * scale_s[k]);
    size_t o = ((size_t)(k >> 3)*128 + col)*8 + (k & 7);
    Wfh[o] = t.x; Wfl[o] = t.y;
    cpart += shift_s[k] * w;
  }
  atomicAdd(&cvec[col], cpart);
}

// ---------------------------------------------------------------------------
extern "C" void kernel_launch(void* const* d_in, const int* in_sizes, int n_in,
                              void* d_out, int out_size, void* d_ws, size_t ws_size,
                              hipStream_t stream)
{
  const float* node_feat = (const float*)d_in[0];
  const float* edge_feat = (const float*)d_in[1];
  const int*   edge_index = (const int*)d_in[2];
  const int* src = edge_index;
  const int* dst = edge_index + NE;

  const float* enW1 = (const float*)d_in[3];  const float* enb1 = (const float*)d_in[4];
  const float* enW2 = (const float*)d_in[5];  const float* enb2 = (const float*)d_in[6];
  const float* enW3 = (const float*)d_in[7];  const float* enb3 = (const float*)d_in[8];
  const float* enlg = (const float*)d_in[9];  const float* enlb = (const float*)d_in[10];

  const float* eeW1 = (const float*)d_in[11]; const float* eeb1 = (const float*)d_in[12];
  const float* eeW2 = (const float*)d_in[13]; const float* eeb2 = (const float*)d_in[14];
  const float* eeW3 = (const float*)d_in[15]; const float* eeb3 = (const float*)d_in[16];
  const float* eelg = (const float*)d_in[17]; const float* eelb = (const float*)d_in[18];

  const float* procW = (const float*)d_in[19];
  const float* procB = (const float*)d_in[20];
  const float* bnG   = (const float*)d_in[21];
  const float* bnB   = (const float*)d_in[22];

  const float* dW1 = (const float*)d_in[23]; const float* db1 = (const float*)d_in[24];
  const float* dW2 = (const float*)d_in[25]; const float* db2 = (const float*)d_in[26];
  const float* dW3 = (const float*)d_in[27]; const float* db3 = (const float*)d_in[28];
  const float* dlg = (const float*)d_in[29]; const float* dlb = (const float*)d_in[30];

  char* ws = (char*)d_ws;
  size_t off = 0;
  auto alloc = [&](size_t bytes) -> void* {
    void* p = ws + off;
    off = (off + bytes + 255) & ~(size_t)255;
    return p;
  };
  float* hn     = (float*)alloc((size_t)NN*DD*4);
  unsigned short* hbf = (unsigned short*)alloc((size_t)NN*DD*2);  // bf16 gather table
  unsigned short* ybf = (unsigned short*)alloc((size_t)NN*DD*2);  // bf16 y (BN input)
  float* dis    = (float*)alloc(NN*4);
  float* invcnt = (float*)alloc(NN*4);
  float* bnsums5 = (float*)alloc(5*3*DD*4);  // 5 steps x [sum, sumsq, cvec]
  int* deg    = (int*)alloc(NN*4);
  int* cnt    = (int*)alloc(NN*4);
  int* rowptr = (int*)alloc((NN+1)*4);
  int* nextp  = (int*)alloc(NN*4);
  int* srow   = (int*)alloc((NN+1)*4);
  int* nexts  = (int*)alloc(NN*4);
  int* csr    = (int*)alloc((size_t)NE*4);
  int* eperm  = (int*)alloc((size_t)NE*4);
  int* srcsorted = (int*)alloc((size_t)NE*4);
  auto allocW = [&](int kp) { return (short*)alloc((size_t)kp*128*2); };
  short *pN1h=allocW(32),  *pN1l=allocW(32);
  short *pN2h=allocW(128), *pN2l=allocW(128);
  short *pN3h=allocW(128), *pN3l=allocW(128);
  short *pE1h=allocW(32),  *pE1l=allocW(32);
  short *pE2h=allocW(128), *pE2l=allocW(128);
  short *pE3h=allocW(128), *pE3l=allocW(128);
  short *pD1h=allocW(128), *pD1l=allocW(128);
  short *pD2h=allocW(128), *pD2l=allocW(128);
  short *pD3h=allocW(128), *pD3l=allocW(128);
  short *pP0h[5], *pP0l[5];
  for (int s = 0; s < 5; s++) { pP0h[s]=allocW(128); pP0l[s]=allocW(128); }
  short *pWfh=allocW(128), *pWfl=allocW(128);

  (void)hipMemsetAsync(deg, 0, NN*4, stream);
  (void)hipMemsetAsync(cnt, 0, NN*4, stream);
  (void)hipMemsetAsync(bnsums5, 0, 5*3*DD*4, stream);

  // pack static weights: 12 K=128 mats in one launch + 1 small 2D launch
  PackArgs pa;
  const float* s128[NPACK] = { enW2, enW3, eeW2, eeW3, dW1, dW2, dW3,
                               procW + 0*(size_t)DD*DD*2, procW + 1*(size_t)DD*DD*2,
                               procW + 2*(size_t)DD*DD*2, procW + 3*(size_t)DD*DD*2,
                               procW + 4*(size_t)DD*DD*2 };
  short* d128h[NPACK] = { pN2h, pN3h, pE2h, pE3h, pD1h, pD2h, pD3h,
                          pP0h[0], pP0h[1], pP0h[2], pP0h[3], pP0h[4] };
  short* d128l[NPACK] = { pN2l, pN3l, pE2l, pE3l, pD1l, pD2l, pD3l,
                          pP0l[0], pP0l[1], pP0l[2], pP0l[3], pP0l[4] };
  for (int m = 0; m < NPACK; m++) { pa.src[m]=s128[m]; pa.dh[m]=d128h[m]; pa.dl[m]=d128l[m]; }
  pack_many_kernel<<<dim3(64, NPACK), 256, 0, stream>>>(pa);
  pack_small_kernel<<<dim3(16, 2), 256, 0, stream>>>(enW1, pN1h, pN1l, eeW1, eeb1, pE1h);

  // graph setup
  count_kernel<<<(NE+255)/256, 256, 0, stream>>>(src, dst, cnt, deg);
  scan2_kernel<<<2, 256, 0, stream>>>(deg, rowptr, nextp, dis, cnt, srow, nexts, invcnt);
  fill_both_kernel<<<(NE+255)/256, 256, 0, stream>>>(src, dst, nextp, csr, nexts, eperm, srcsorted);

  const int GN  = (NN + 127) / 128;  // 391
  const int GE  = NE / 128;          // 6250
  const int GG  = (NN + 63) / 64;    // 782
  const dim3 GAS(NN/16, 4);          // sliced agg: 3125 x 4 slices

  // encoders: node MLP writes hn, edge MLP atomically adds scatter-mean into hn
  mlp_mfma_kernel<19, false><<<GN, 256, 0, stream>>>(node_feat, NN,
      pN1h, pN1l, enb1, pN2h, pN2l, enb2, pN3h, pN3l, enb3, enlg, enlb, hn,
      nullptr, nullptr, nullptr);
  mlp_mfma_kernel<4, true><<<GE, 256, 0, stream>>>(edge_feat, NE,
      pE1h, pE1l, eeb1, pE2h, pE2l, eeb2, pE3h, pE3l, eeb3, eelg, eelb, hn,
      srcsorted, eperm, invcnt);

  // processor: 5 residual (conv -> leaky -> BN -> conv) steps
  for (int s = 0; s < 5; s++) {
    const float* Wc2 = procW + (size_t)(s*2+1)*DD*DD;
    const float* b0  = procB + (size_t)(s*2+0)*DD;
    const float* b1p = procB + (size_t)(s*2+1)*DD;
    float* sums = bnsums5 + (size_t)s*3*DD;
    float* cvec = sums + 2*DD;

    gemm_mfma_kernel<<<GG, 256, 0, stream>>>(hn, pP0h[s], pP0l[s], nullptr, dis, hbf, NN);
    gcn_agg_kernel<<<GAS, 256, 0, stream>>>((const unsigned*)hbf, rowptr, csr, dis,
                                            b0, nullptr, nullptr, (unsigned*)ybf, 0);
    bn_stats_kernel<<<512, 256, 0, stream>>>((const unsigned*)ybf, sums);
    bn_fold_kernel<<<16, 256, 0, stream>>>(sums, bnG + s*DD, bnB + s*DD, Wc2, pWfh, pWfl, cvec);
    gemm_bf_mfma_kernel<<<GG, 256, 0, stream>>>(ybf, pWfh, pWfl, cvec, dis, hbf, NN);
    gcn_agg_kernel<<<GAS, 256, 0, stream>>>((const unsigned*)hbf, rowptr, csr, dis,
                                            b1p, hn, hn, nullptr, 1);
  }

  // decoder -> d_out (fp32)
  mlp_mfma_kernel<128, false><<<GN, 256, 0, stream>>>(hn, NN,
      pD1h, pD1l, db1, pD2h, pD2l, db2, pD3h, pD3l, db3, dlg, dlb, (float*)d_out,
      nullptr, nullptr, nullptr);
}

// Round 6
// 1368.026 us; speedup vs baseline: 1.1113x; 1.1113x over previous
//
#include <hip/hip_runtime.h>

#define NN 50000
#define NE 800000
#define DD 128
#define LN_EPS 1e-5f

typedef __attribute__((ext_vector_type(8))) short v8s;    // 8 bf16
typedef __attribute__((ext_vector_type(4))) unsigned v4u; // same 16B as v8s
typedef __attribute__((ext_vector_type(4))) float f32x4;  // MFMA acc
typedef __attribute__((ext_vector_type(2))) float f32x2;  // packed-f32 pair

union CvtHL { v4u u; v8s s; };

__device__ __forceinline__ float leakyf(float x){ return x > 0.f ? x : 0.05f*x; }
__device__ __forceinline__ short f2bf(float f){
  unsigned u = __float_as_uint(f);
  u = (u + 0x7fffu + ((u >> 16) & 1u)) >> 16;   // RNE
  return (short)u;
}
__device__ __forceinline__ float bf2f(unsigned short h){
  return __uint_as_float(((unsigned)h) << 16);
}
// HW RNE pack: low16 = bf16(a), high16 = bf16(b). 1 inst for 2 values.
__device__ __forceinline__ unsigned cvt_pk_bf16(float a, float b){
  unsigned r;
  asm("v_cvt_pk_bf16_f32 %0, %1, %2" : "=v"(r) : "v"(a), "v"(b));
  return r;
}
// packed f32 math (CDNA VOP3P): 2 floats / instruction
__device__ __forceinline__ f32x2 pk_add(f32x2 a, f32x2 b){
  f32x2 r; asm("v_pk_add_f32 %0, %1, %2" : "=v"(r) : "v"(a), "v"(b)); return r;
}
__device__ __forceinline__ f32x2 pk_mul(f32x2 a, f32x2 b){
  f32x2 r; asm("v_pk_mul_f32 %0, %1, %2" : "=v"(r) : "v"(a), "v"(b)); return r;
}
// [hi16(u0) | hi16(u1)<<16] in one v_perm_b32
__device__ __forceinline__ unsigned pack_hi16(unsigned u0, unsigned u1){
  return __builtin_amdgcn_perm(u1, u0, 0x07060302u);
}
// split fp32 -> {hi, lo}: hi = truncated top-16 (cheap), lo = RNE(residual).
__device__ __forceinline__ short2 f2bf2v(float v){
  unsigned u = __float_as_uint(v);
  short hi = (short)(u >> 16);
  float lo = v - __uint_as_float(u & 0xffff0000u);
  return make_short2(hi, f2bf(lo));
}

// ---------------------------------------------------------------------------
// Weight packing. Layout: [(k>>3)*128+n][k&7] hi/lo bf16 planes.
// pack_small: y=0 node-encoder W1 (K=19 padded to 32) -> hi/lo planes;
//             y=1 edge-encoder W1+b1 folded single plane (see below).
// ---------------------------------------------------------------------------
__global__ void pack_small_kernel(const float* __restrict__ nW1,
                                  short* __restrict__ nWh, short* __restrict__ nWl,
                                  const float* __restrict__ eW1, const float* __restrict__ eb1,
                                  short* __restrict__ eWp)
{
  int idx = blockIdx.x*256 + threadIdx.x;   // 0..4095
  int k = idx >> 7, n = idx & 127;
  size_t o = ((size_t)(k >> 3)*128 + n)*8 + (k & 7);
  if (blockIdx.y == 0) {
    float v = (k < 19) ? nW1[k*128 + n] : 0.f;
    short2 t = f2bf2v(v);
    nWh[o] = t.x; nWl[o] = t.y;
  } else {
    // rows 0-3: hi(W1) (pairs A=xh); 4-7: lo(W1) (A=xh); 8-11: hi(W1) (A=xl);
    // 12: hi(b1), 13: lo(b1) (A=1.0); rest 0. One MFMA = xh@Wh+xh@Wl+xl@Wh+b1.
    short v = 0;
    if (k < 4)        v = f2bf2v(eW1[k*128 + n]).x;
    else if (k < 8)   v = f2bf2v(eW1[(k-4)*128 + n]).y;
    else if (k < 12)  v = f2bf2v(eW1[(k-8)*128 + n]).x;
    else if (k == 12) v = f2bf2v(eb1[n]).x;
    else if (k == 13) v = f2bf2v(eb1[n]).y;
    eWp[o] = v;
  }
}

#define NPACK 12
struct PackArgs { const float* src[NPACK]; short* dh[NPACK]; short* dl[NPACK]; };

// all-K=128 batch pack: grid (64, NPACK)
__global__ void pack_many_kernel(PackArgs pa)
{
  int m = blockIdx.y;
  int idx = blockIdx.x*256 + threadIdx.x;   // 0..16383
  int k = idx >> 7, n = idx & 127;
  float v = pa.src[m][k*128 + n];
  short2 t = f2bf2v(v);
  size_t o = ((size_t)(k >> 3)*128 + n)*8 + (k & 7);
  pa.dh[m][o] = t.x; pa.dl[m][o] = t.y;
}

// full split-split product (A has hi+lo)
#define MFMA3(ah, al, bh, bl, ac) \
  ac = __builtin_amdgcn_mfma_f32_16x16x32_bf16(al, bh, ac, 0,0,0); \
  ac = __builtin_amdgcn_mfma_f32_16x16x32_bf16(ah, bl, ac, 0,0,0); \
  ac = __builtin_amdgcn_mfma_f32_16x16x32_bf16(ah, bh, ac, 0,0,0);

// A exact-bf16 (no lo plane): 2 MFMAs
#define MFMA2(ah, bh, bl, ac) \
  ac = __builtin_amdgcn_mfma_f32_16x16x32_bf16(ah, bl, ac, 0,0,0); \
  ac = __builtin_amdgcn_mfma_f32_16x16x32_bf16(ah, bh, ac, 0,0,0);

// 8 fp32 -> hi-plane (v_perm pack) + lo-plane (cvt_pk RNE)
#define SPLIT8(f0, f1, h, l) { \
  unsigned u0=__float_as_uint(f0.x), u1=__float_as_uint(f0.y), u2=__float_as_uint(f0.z), u3=__float_as_uint(f0.w); \
  unsigned u4=__float_as_uint(f1.x), u5=__float_as_uint(f1.y), u6=__float_as_uint(f1.z), u7=__float_as_uint(f1.w); \
  CvtHL ch_, cl_; \
  ch_.u = (v4u){ pack_hi16(u0,u1), pack_hi16(u2,u3), pack_hi16(u4,u5), pack_hi16(u6,u7) }; \
  cl_.u = (v4u){ \
    cvt_pk_bf16(f0.x-__uint_as_float(u0&0xffff0000u), f0.y-__uint_as_float(u1&0xffff0000u)), \
    cvt_pk_bf16(f0.z-__uint_as_float(u2&0xffff0000u), f0.w-__uint_as_float(u3&0xffff0000u)), \
    cvt_pk_bf16(f1.x-__uint_as_float(u4&0xffff0000u), f1.y-__uint_as_float(u5&0xffff0000u)), \
    cvt_pk_bf16(f1.z-__uint_as_float(u6&0xffff0000u), f1.w-__uint_as_float(u7&0xffff0000u)) }; \
  h = ch_.s; l = cl_.s; }

// bias + leaky + bf16-pack on paired acc halves. Bit-identical to the scalar
// version: x=acc+bv (pk_add), m=0.05*x (pk_mul), max, HW-RNE cvt.
#define EPI_PK(accv, bv2, DOBIAS, p01, p23) { \
  f32x2 x01 = (f32x2){(accv)[0], (accv)[1]}; \
  f32x2 x23 = (f32x2){(accv)[2], (accv)[3]}; \
  if (DOBIAS) { x01 = pk_add(x01, bv2); x23 = pk_add(x23, bv2); } \
  f32x2 m01 = pk_mul(x01, (f32x2)(0.05f)); \
  f32x2 m23 = pk_mul(x23, (f32x2)(0.05f)); \
  p01 = cvt_pk_bf16(fmaxf(x01.x, m01.x), fmaxf(x01.y, m01.y)); \
  p23 = cvt_pk_bf16(fmaxf(x23.x, m23.x), fmaxf(x23.y, m23.y)); }

// ---------------------------------------------------------------------------
// 3-layer MLP + LayerNorm. Layer-1 inputs and all weights hi/lo split;
// hidden activations single-bf16 (layers 2/3 use 2 MFMAs).
// SCATTER (edge): layer-1 uses the single-plane combined weight (1 MFMA/tile,
// bias folded into K); LN stats use a shared reduce-scatter butterfly;
// seg-reduce flushes are pre-scaled by invcnt[src] and land directly in hn
// (scatter-MEAN fused -> no esum buffer / memset / addmean pass).
// ---------------------------------------------------------------------------
template<int IN_W, bool SCATTER>
__global__ __launch_bounds__(256)
void mlp_mfma_kernel(const float* __restrict__ x, int nrows,
                     const short* __restrict__ W1h, const short* __restrict__ W1l,
                     const float* __restrict__ b1,
                     const short* __restrict__ W2h, const short* __restrict__ W2l,
                     const float* __restrict__ b2,
                     const short* __restrict__ W3h, const short* __restrict__ W3l,
                     const float* __restrict__ b3,
                     const float* __restrict__ g, const float* __restrict__ bb,
                     float* __restrict__ out,
                     const int* __restrict__ sidx,   // src-sorted src values
                     const int* __restrict__ eperm,  // sorted pos -> edge id
                     const float* __restrict__ invcnt) // 1/max(cnt,1) per node
{
  constexpr int L1K = (IN_W + 31) / 32;
  constexpr bool EDGE1 = (SCATTER && IN_W == 4);
  __shared__ __align__(16) short Hh[128*136];   // act plane; reused (stride 132) as bf16 seg buffer
  __shared__ float lnS[128][2], lnQ[128][2];
  __shared__ int sidx_s[128];
  __shared__ __align__(16) uint4 xstage[SCATTER ? 128 : 1];  // pre-split hi/lo packs

  const int tid  = threadIdx.x;
  const int lane = tid & 63, wave = tid >> 6;
  const int wr = wave >> 1, wc = wave & 1;
  const int quad = lane >> 4, low = lane & 15;
  const int row0 = blockIdx.x * 128;

  if (SCATTER) {
    // 128 parallel scattered gathers + hi/lo split -> LDS stage
    if (tid < 128) {
      int e = eperm[row0 + tid];           // NE % 128 == 0
      float4 f = ((const float4*)x)[e];
      unsigned u0=__float_as_uint(f.x), u1=__float_as_uint(f.y);
      unsigned u2=__float_as_uint(f.z), u3=__float_as_uint(f.w);
      uint4 st;
      st.x = pack_hi16(u0,u1);
      st.y = pack_hi16(u2,u3);
      st.z = cvt_pk_bf16(f.x-__uint_as_float(u0&0xffff0000u), f.y-__uint_as_float(u1&0xffff0000u));
      st.w = cvt_pk_bf16(f.z-__uint_as_float(u2&0xffff0000u), f.w-__uint_as_float(u3&0xffff0000u));
      xstage[tid] = st;
      sidx_s[tid] = sidx[row0 + tid];
    }
    __syncthreads();
  }

  f32x4 acc[4][4];

  // ---------------- layer 1 ----------------
  #pragma unroll
  for (int tm=0;tm<4;tm++)
    #pragma unroll
    for (int tn=0;tn<4;tn++) acc[tm][tn] = (f32x4)0.f;

  if constexpr (EDGE1) {
    // single-plane: K slots 0-7 = xh (pairs Wh,Wl rows), 8-11 = xl (pairs Wh),
    // 12-13 = 1.0 (pairs b1 hi/lo rows). One MFMA per tile.
    v8s ah[4], bh[4];
    #pragma unroll
    for (int tm=0;tm<4;tm++) {
      int lr = wr*64 + tm*16 + low;
      v8s h = (v8s)0;
      if (quad == 0) {
        uint4 st = xstage[lr];
        CvtHL c_; c_.u = (v4u){ st.x, st.y, st.x, st.y };
        h = c_.s;
      } else if (quad == 1) {
        uint4 st = xstage[lr];
        CvtHL c_; c_.u = (v4u){ st.z, st.w, 0x3F803F80u, 0u };
        h = c_.s;
      }
      ah[tm] = h;
    }
    #pragma unroll
    for (int tn=0;tn<4;tn++) {
      size_t o = ((size_t)quad*128 + wc*64 + tn*16 + low)*8;
      bh[tn] = *(const v8s*)(W1h + o);
    }
    #pragma unroll
    for (int tm=0;tm<4;tm++)
      #pragma unroll
      for (int tn=0;tn<4;tn++)
        acc[tm][tn] = __builtin_amdgcn_mfma_f32_16x16x32_bf16(ah[tm], bh[tn], acc[tm][tn], 0,0,0);
  } else {
    for (int ks = 0; ks < L1K; ks++) {
      v8s ah[4], al[4], bh[4], bl[4];
      #pragma unroll
      for (int tm=0;tm<4;tm++) {
        int lr = wr*64 + tm*16 + low;
        v8s h = (v8s)0, l = (v8s)0;
        if (IN_W % 32 == 0) {
          int r = row0 + lr;
          if (r < nrows) {
            const float* p = x + (size_t)r*IN_W + ks*32 + quad*8;
            float4 f0 = *(const float4*)p;
            float4 f1 = *(const float4*)(p + 4);
            SPLIT8(f0, f1, h, l);
          }
        } else {
          int r = row0 + lr;
          #pragma unroll
          for (int j=0;j<8;j++) {
            int k = ks*32 + quad*8 + j;
            if (k < IN_W && r < nrows) {
              short2 t = f2bf2v(x[(size_t)r*IN_W + k]);
              h[j] = t.x; l[j] = t.y;
            }
          }
        }
        ah[tm] = h; al[tm] = l;
      }
      #pragma unroll
      for (int tn=0;tn<4;tn++) {
        size_t o = ((size_t)(ks*4+quad)*128 + wc*64 + tn*16 + low)*8;
        bh[tn] = *(const v8s*)(W1h + o);
        bl[tn] = *(const v8s*)(W1l + o);
      }
      #pragma unroll
      for (int tm=0;tm<4;tm++)
        #pragma unroll
        for (int tn=0;tn<4;tn++) { MFMA3(ah[tm], al[tm], bh[tn], bl[tn], acc[tm][tn]); }
    }
  }
  #pragma unroll
  for (int tn=0;tn<4;tn++) {
    float bv = EDGE1 ? 0.f : b1[wc*64 + tn*16 + low];
    f32x2 bv2 = (f32x2)(bv);
    #pragma unroll
    for (int tm=0;tm<4;tm++) {
      unsigned p01, p23;
      EPI_PK(acc[tm][tn], bv2, !EDGE1, p01, p23);
      int base = (wr*64+tm*16+quad*4)*136 + wc*64+tn*16+low;
      Hh[base]     = (short)p01;
      Hh[base+136] = (short)(p01>>16);
      Hh[base+272] = (short)p23;
      Hh[base+408] = (short)(p23>>16);
    }
  }
  __syncthreads();

  // ---------------- layer 2 (bf16 A from LDS, 2 MFMAs) ----------------
  #pragma unroll
  for (int tm=0;tm<4;tm++)
    #pragma unroll
    for (int tn=0;tn<4;tn++) acc[tm][tn] = (f32x4)0.f;
  #pragma unroll
  for (int ks=0;ks<4;ks++) {
    v8s ah[4], bh[4], bl[4];
    #pragma unroll
    for (int tm=0;tm<4;tm++)
      ah[tm] = *(const v8s*)&Hh[(wr*64+tm*16+low)*136 + ks*32 + quad*8];
    #pragma unroll
    for (int tn=0;tn<4;tn++) {
      size_t o = ((size_t)(ks*4+quad)*128 + wc*64 + tn*16 + low)*8;
      bh[tn] = *(const v8s*)(W2h + o);
      bl[tn] = *(const v8s*)(W2l + o);
    }
    #pragma unroll
    for (int tm=0;tm<4;tm++)
      #pragma unroll
      for (int tn=0;tn<4;tn++) { MFMA2(ah[tm], bh[tn], bl[tn], acc[tm][tn]); }
  }
  __syncthreads();
  #pragma unroll
  for (int tn=0;tn<4;tn++) {
    float bv = b2[wc*64 + tn*16 + low];
    f32x2 bv2 = (f32x2)(bv);
    #pragma unroll
    for (int tm=0;tm<4;tm++) {
      unsigned p01, p23;
      EPI_PK(acc[tm][tn], bv2, true, p01, p23);
      int base = (wr*64+tm*16+quad*4)*136 + wc*64+tn*16+low;
      Hh[base]     = (short)p01;
      Hh[base+136] = (short)(p01>>16);
      Hh[base+272] = (short)p23;
      Hh[base+408] = (short)(p23>>16);
    }
  }
  __syncthreads();

  // ---------------- layer 3 (bf16 A from LDS, 2 MFMAs) ----------------
  #pragma unroll
  for (int tm=0;tm<4;tm++)
    #pragma unroll
    for (int tn=0;tn<4;tn++) acc[tm][tn] = (f32x4)0.f;
  #pragma unroll
  for (int ks=0;ks<4;ks++) {
    v8s ah[4], bh[4], bl[4];
    #pragma unroll
    for (int tm=0;tm<4;tm++)
      ah[tm] = *(const v8s*)&Hh[(wr*64+tm*16+low)*136 + ks*32 + quad*8];
    #pragma unroll
    for (int tn=0;tn<4;tn++) {
      size_t o = ((size_t)(ks*4+quad)*128 + wc*64 + tn*16 + low)*8;
      bh[tn] = *(const v8s*)(W3h + o);
      bl[tn] = *(const v8s*)(W3l + o);
    }
    #pragma unroll
    for (int tm=0;tm<4;tm++)
      #pragma unroll
      for (int tn=0;tn<4;tn++) { MFMA2(ah[tm], bh[tn], bl[tn], acc[tm][tn]); }
  }
  #pragma unroll
  for (int tn=0;tn<4;tn++) {
    float bv = b3[wc*64 + tn*16 + low];
    #pragma unroll
    for (int tm=0;tm<4;tm++)
      #pragma unroll
      for (int i=0;i<4;i++) acc[tm][tn][i] += bv;
  }

  // ---------------- fused LayerNorm ----------------
  // Reduce-scatter butterfly: all 16 (tm,i) row-reductions share one 4-step
  // butterfly (masks 1,2,4,8 — identical tree association, bit-identical).
  {
    float ct[16];
    #pragma unroll
    for (int tm=0;tm<4;tm++)
      #pragma unroll
      for (int i=0;i<4;i++)
        ct[tm*4+i] = acc[tm][0][i] + acc[tm][1][i] + acc[tm][2][i] + acc[tm][3][i];
    #pragma unroll
    for (int st=0; st<4; st++) {
      const int mm = 1 << st;
      const bool hbit = ((low >> st) & 1) != 0;
      #pragma unroll
      for (int p=0; p < (16>>st); p+=2) {
        float snd = hbit ? ct[p]   : ct[p+1];
        float kp  = hbit ? ct[p+1] : ct[p];
        ct[p>>1] = kp + __shfl_xor(snd, mm);
      }
    }
    { int r = wr*64 + (low>>2)*16 + quad*4 + (low&3); lnS[r][wc] = ct[0]; }
    #pragma unroll
    for (int tm=0;tm<4;tm++)
      #pragma unroll
      for (int i=0;i<4;i++)
        ct[tm*4+i] = acc[tm][0][i]*acc[tm][0][i] + acc[tm][1][i]*acc[tm][1][i]
                   + acc[tm][2][i]*acc[tm][2][i] + acc[tm][3][i]*acc[tm][3][i];
    #pragma unroll
    for (int st=0; st<4; st++) {
      const int mm = 1 << st;
      const bool hbit = ((low >> st) & 1) != 0;
      #pragma unroll
      for (int p=0; p < (16>>st); p+=2) {
        float snd = hbit ? ct[p]   : ct[p+1];
        float kp  = hbit ? ct[p+1] : ct[p];
        ct[p>>1] = kp + __shfl_xor(snd, mm);
      }
    }
    { int r = wr*64 + (low>>2)*16 + quad*4 + (low&3); lnQ[r][wc] = ct[0]; }
  }
  __syncthreads();   // all layer-3 H reads done (act-plane reuse below is safe)

  float g4[4], bb4[4];
  #pragma unroll
  for (int tn=0;tn<4;tn++) { int c = wc*64+tn*16+low; g4[tn] = g[c]; bb4[tn] = bb[c]; }

  #pragma unroll
  for (int tm=0;tm<4;tm++)
    #pragma unroll
    for (int i=0;i<4;i++) {
      int r = wr*64 + tm*16 + quad*4 + i;
      float2 S2 = *(const float2*)&lnS[r][0];
      float2 Q2 = *(const float2*)&lnQ[r][0];
      float s = S2.x + S2.y;
      float q = Q2.x + Q2.y;
      float m = s * (1.f/128.f);
      float var = q * (1.f/128.f) - m*m;
      float rs = rsqrtf(var + LN_EPS);
      int gr = row0 + r;
      if (!SCATTER && gr >= nrows) continue;
      float v0 = (acc[tm][0][i] - m) * rs * g4[0] + bb4[0];
      float v1 = (acc[tm][1][i] - m) * rs * g4[1] + bb4[1];
      float v2 = (acc[tm][2][i] - m) * rs * g4[2] + bb4[2];
      float v3 = (acc[tm][3][i] - m) * rs * g4[3] + bb4[3];
      if (SCATTER) {
        unsigned p01 = cvt_pk_bf16(v0, v1), p23 = cvt_pk_bf16(v2, v3);
        int base = r*132 + wc*64 + low;
        Hh[base]    = (short)p01;      // bf16 stage for seg-reduce
        Hh[base+16] = (short)(p01>>16);
        Hh[base+32] = (short)p23;
        Hh[base+48] = (short)(p23>>16);
      } else {
        size_t ob = (size_t)gr*DD + wc*64 + low;
        out[ob]    = v0;
        out[ob+16] = v1;
        out[ob+32] = v2;
        out[ob+48] = v3;
      }
    }

  if (SCATTER) {
    __syncthreads();
    // dword-vectorized seg-reduce: wave g handles rows [g*32, g*32+32),
    // 64 col-pairs; flushes scaled by invcnt[cur] straight into hn.
    const unsigned* H32 = (const unsigned*)Hh;    // row stride 66 dwords
    int cp = tid & 63;
    int gI = tid >> 6;
    int rbeg = gI*32, rend = rbeg + 32;
    unsigned pv = H32[rbeg*66 + cp];
    float a0 = __uint_as_float(pv << 16), a1 = __uint_as_float(pv & 0xffff0000u);
    int cur = __builtin_amdgcn_readfirstlane(sidx_s[rbeg]);
    for (int r = rbeg + 1; r < rend; r++) {
      int sv = __builtin_amdgcn_readfirstlane(sidx_s[r]);   // wave-uniform scalar
      unsigned hv = H32[r*66 + cp];
      if (sv != cur) {
        float ic = invcnt[cur];
        atomicAdd(&out[(size_t)cur*DD + 2*cp],     a0*ic);
        atomicAdd(&out[(size_t)cur*DD + 2*cp + 1], a1*ic);
        a0 = __uint_as_float(hv << 16); a1 = __uint_as_float(hv & 0xffff0000u);
        cur = sv;
      } else {
        a0 += __uint_as_float(hv << 16); a1 += __uint_as_float(hv & 0xffff0000u);
      }
    }
    float ic = invcnt[cur];
    atomicAdd(&out[(size_t)cur*DD + 2*cp],     a0*ic);
    atomicAdd(&out[(size_t)cur*DD + 2*cp + 1], a1*ic);
  }
}

// ---------------------------------------------------------------------------
// outbf[r] = bf16((x[r] @ W + initv) * rowscale[r])  — fp32 input (split, 3 MFMA)
// ---------------------------------------------------------------------------
__global__ __launch_bounds__(256)
void gemm_mfma_kernel(const float* __restrict__ x,
                      const short* __restrict__ Wh, const short* __restrict__ Wl,
                      const float* __restrict__ initv, const float* __restrict__ rowscale,
                      unsigned short* __restrict__ outbf, int nrows)
{
  const int tid  = threadIdx.x;
  const int lane = tid & 63, wave = tid >> 6;
  const int wr = wave >> 1, wc = wave & 1;
  const int quad = lane >> 4, low = lane & 15;
  const int row0 = blockIdx.x * 64;

  f32x4 acc[2][4];
  #pragma unroll
  for (int tm=0;tm<2;tm++)
    #pragma unroll
    for (int tn=0;tn<4;tn++) acc[tm][tn] = (f32x4)0.f;

  #pragma unroll
  for (int ks=0;ks<4;ks++) {
    v8s ah[2], al[2], bh[4], bl[4];
    #pragma unroll
    for (int tm=0;tm<2;tm++) {
      int r = row0 + wr*32 + tm*16 + low;
      v8s h = (v8s)0, l = (v8s)0;
      if (r < nrows) {
        const float* p = x + (size_t)r*DD + ks*32 + quad*8;
        float4 f0 = *(const float4*)p;
        float4 f1 = *(const float4*)(p + 4);
        SPLIT8(f0, f1, h, l);
      }
      ah[tm] = h; al[tm] = l;
    }
    #pragma unroll
    for (int tn=0;tn<4;tn++) {
      size_t o = ((size_t)(ks*4+quad)*128 + wc*64 + tn*16 + low)*8;
      bh[tn] = *(const v8s*)(Wh + o);
      bl[tn] = *(const v8s*)(Wl + o);
    }
    #pragma unroll
    for (int tm=0;tm<2;tm++)
      #pragma unroll
      for (int tn=0;tn<4;tn++) { MFMA3(ah[tm], al[tm], bh[tn], bl[tn], acc[tm][tn]); }
  }

  float iv4[4];
  #pragma unroll
  for (int tn=0;tn<4;tn++) iv4[tn] = initv ? initv[wc*64 + tn*16 + low] : 0.f;

  #pragma unroll
  for (int tm=0;tm<2;tm++)
    #pragma unroll
    for (int i=0;i<4;i++) {
      int gr = row0 + wr*32 + tm*16 + quad*4 + i;
      if (gr >= nrows) continue;
      float sc = rowscale ? rowscale[gr] : 1.f;
      float v0 = (acc[tm][0][i] + iv4[0]) * sc;
      float v1 = (acc[tm][1][i] + iv4[1]) * sc;
      float v2 = (acc[tm][2][i] + iv4[2]) * sc;
      float v3 = (acc[tm][3][i] + iv4[3]) * sc;
      unsigned p01 = cvt_pk_bf16(v0, v1), p23 = cvt_pk_bf16(v2, v3);
      size_t base = (size_t)gr*DD + wc*64 + low;
      outbf[base]    = (unsigned short)p01;
      outbf[base+16] = (unsigned short)(p01>>16);
      outbf[base+32] = (unsigned short)p23;
      outbf[base+48] = (unsigned short)(p23>>16);
    }
}

// ---------------------------------------------------------------------------
// Pre-split hi/lo-plane input (from agg1 epilogue): 16 B/lane A-loads, no
// SPLIT8 VALU, same MFMA3 order -> bit-identical to the fp32 path.
// ---------------------------------------------------------------------------
__global__ __launch_bounds__(256)
void gemm_pl_mfma_kernel(const unsigned short* __restrict__ xh,
                         const unsigned short* __restrict__ xl,
                         const short* __restrict__ Wh, const short* __restrict__ Wl,
                         const float* __restrict__ initv, const float* __restrict__ rowscale,
                         unsigned short* __restrict__ outbf, int nrows)
{
  const int tid  = threadIdx.x;
  const int lane = tid & 63, wave = tid >> 6;
  const int wr = wave >> 1, wc = wave & 1;
  const int quad = lane >> 4, low = lane & 15;
  const int row0 = blockIdx.x * 64;

  f32x4 acc[2][4];
  #pragma unroll
  for (int tm=0;tm<2;tm++)
    #pragma unroll
    for (int tn=0;tn<4;tn++) acc[tm][tn] = (f32x4)0.f;

  #pragma unroll
  for (int ks=0;ks<4;ks++) {
    v8s ah[2], al[2], bh[4], bl[4];
    #pragma unroll
    for (int tm=0;tm<2;tm++) {
      int r = row0 + wr*32 + tm*16 + low;
      size_t xo = (size_t)r*DD + ks*32 + quad*8;
      ah[tm] = (r < nrows) ? *(const v8s*)(xh + xo) : (v8s)0;
      al[tm] = (r < nrows) ? *(const v8s*)(xl + xo) : (v8s)0;
    }
    #pragma unroll
    for (int tn=0;tn<4;tn++) {
      size_t o = ((size_t)(ks*4+quad)*128 + wc*64 + tn*16 + low)*8;
      bh[tn] = *(const v8s*)(Wh + o);
      bl[tn] = *(const v8s*)(Wl + o);
    }
    #pragma unroll
    for (int tm=0;tm<2;tm++)
      #pragma unroll
      for (int tn=0;tn<4;tn++) { MFMA3(ah[tm], al[tm], bh[tn], bl[tn], acc[tm][tn]); }
  }

  float iv4[4];
  #pragma unroll
  for (int tn=0;tn<4;tn++) iv4[tn] = initv ? initv[wc*64 + tn*16 + low] : 0.f;

  #pragma unroll
  for (int tm=0;tm<2;tm++)
    #pragma unroll
    for (int i=0;i<4;i++) {
      int gr = row0 + wr*32 + tm*16 + quad*4 + i;
      if (gr >= nrows) continue;
      float sc = rowscale ? rowscale[gr] : 1.f;
      float v0 = (acc[tm][0][i] + iv4[0]) * sc;
      float v1 = (acc[tm][1][i] + iv4[1]) * sc;
      float v2 = (acc[tm][2][i] + iv4[2]) * sc;
      float v3 = (acc[tm][3][i] + iv4[3]) * sc;
      unsigned p01 = cvt_pk_bf16(v0, v1), p23 = cvt_pk_bf16(v2, v3);
      size_t base = (size_t)gr*DD + wc*64 + low;
      outbf[base]    = (unsigned short)p01;
      outbf[base+16] = (unsigned short)(p01>>16);
      outbf[base+32] = (unsigned short)p23;
      outbf[base+48] = (unsigned short)(p23>>16);
    }
}

// ---------------------------------------------------------------------------
// Same but bf16 input (exact, 2 MFMA, 16 B/lane A-loads) — conv2 on y.
// ---------------------------------------------------------------------------
__global__ __launch_bounds__(256)
void gemm_bf_mfma_kernel(const unsigned short* __restrict__ xb,
                         const short* __restrict__ Wh, const short* __restrict__ Wl,
                         const float* __restrict__ initv, const float* __restrict__ rowscale,
                         unsigned short* __restrict__ outbf, int nrows)
{
  const int tid  = threadIdx.x;
  const int lane = tid & 63, wave = tid >> 6;
  const int wr = wave >> 1, wc = wave & 1;
  const int quad = lane >> 4, low = lane & 15;
  const int row0 = blockIdx.x * 64;

  f32x4 acc[2][4];
  #pragma unroll
  for (int tm=0;tm<2;tm++)
    #pragma unroll
    for (int tn=0;tn<4;tn++) acc[tm][tn] = (f32x4)0.f;

  #pragma unroll
  for (int ks=0;ks<4;ks++) {
    v8s ah[2], bh[4], bl[4];
    #pragma unroll
    for (int tm=0;tm<2;tm++) {
      int r = row0 + wr*32 + tm*16 + low;
      ah[tm] = (r < nrows) ? *(const v8s*)(xb + (size_t)r*DD + ks*32 + quad*8) : (v8s)0;
    }
    #pragma unroll
    for (int tn=0;tn<4;tn++) {
      size_t o = ((size_t)(ks*4+quad)*128 + wc*64 + tn*16 + low)*8;
      bh[tn] = *(const v8s*)(Wh + o);
      bl[tn] = *(const v8s*)(Wl + o);
    }
    #pragma unroll
    for (int tm=0;tm<2;tm++)
      #pragma unroll
      for (int tn=0;tn<4;tn++) { MFMA2(ah[tm], bh[tn], bl[tn], acc[tm][tn]); }
  }

  float iv4[4];
  #pragma unroll
  for (int tn=0;tn<4;tn++) iv4[tn] = initv ? initv[wc*64 + tn*16 + low] : 0.f;

  #pragma unroll
  for (int tm=0;tm<2;tm++)
    #pragma unroll
    for (int i=0;i<4;i++) {
      int gr = row0 + wr*32 + tm*16 + quad*4 + i;
      if (gr >= nrows) continue;
      float sc = rowscale ? rowscale[gr] : 1.f;
      float v0 = (acc[tm][0][i] + iv4[0]) * sc;
      float v1 = (acc[tm][1][i] + iv4[1]) * sc;
      float v2 = (acc[tm][2][i] + iv4[2]) * sc;
      float v3 = (acc[tm][3][i] + iv4[3]) * sc;
      unsigned p01 = cvt_pk_bf16(v0, v1), p23 = cvt_pk_bf16(v2, v3);
      size_t base = (size_t)gr*DD + wc*64 + low;
      outbf[base]    = (unsigned short)p01;
      outbf[base+16] = (unsigned short)(p01>>16);
      outbf[base+32] = (unsigned short)p23;
      outbf[base+48] = (unsigned short)(p23>>16);
    }
}

// ---------------------------------------------------------------------------
// GCN aggregation on bf16-packed pre-scaled h. One wave per node; unroll 16/4.
// R1/R4-proven structure: 64 lanes x dword per edge-row -> 16 outstanding
// loads per lane. wave id via readfirstlane -> scalar CSR walk.
// mode 0: outb = bf16(leaky(agg))
// mode 1: outf = resid + agg (fp32); also emits hi/lo bf16 planes (ph/pl)
//         for the next step's plane-fed GEMM (skipped when ph == nullptr).
// ---------------------------------------------------------------------------
__global__ __launch_bounds__(256)
void gcn_agg_kernel(const unsigned* __restrict__ hb, const int* __restrict__ rowptr,
                    const int* __restrict__ csr_src, const float* __restrict__ dis,
                    const float* __restrict__ bias, const float* __restrict__ resid,
                    float* __restrict__ outf, unsigned* __restrict__ outb,
                    unsigned* __restrict__ ph, unsigned* __restrict__ pl, int mode)
{
  const int wv = __builtin_amdgcn_readfirstlane(threadIdx.x >> 6);
  const int lane = threadIdx.x & 63;
  const int i = blockIdx.x*4 + wv;
  if (i >= NN) return;
  unsigned hv = hb[(size_t)i*64 + lane];
  float ax = bf2f((unsigned short)(hv & 0xffff)), ay = bf2f((unsigned short)(hv >> 16));
  const int beg = rowptr[i], end = rowptr[i+1];
  int j = beg;
  for (; j + 16 <= end; j += 16) {
    unsigned v[16];
    #pragma unroll
    for (int k=0;k<16;k++) v[k] = hb[(size_t)csr_src[j+k]*64 + lane];
    #pragma unroll
    for (int k=0;k<16;k++) {
      ax += bf2f((unsigned short)(v[k] & 0xffff));
      ay += bf2f((unsigned short)(v[k] >> 16));
    }
  }
  for (; j + 4 <= end; j += 4) {
    unsigned v[4];
    #pragma unroll
    for (int k=0;k<4;k++) v[k] = hb[(size_t)csr_src[j+k]*64 + lane];
    #pragma unroll
    for (int k=0;k<4;k++) {
      ax += bf2f((unsigned short)(v[k] & 0xffff));
      ay += bf2f((unsigned short)(v[k] >> 16));
    }
  }
  for (; j < end; j++) {
    unsigned v = hb[(size_t)csr_src[j]*64 + lane];
    ax += bf2f((unsigned short)(v & 0xffff));
    ay += bf2f((unsigned short)(v >> 16));
  }
  float di = dis[i];
  float2 bv = ((const float2*)bias)[lane];
  ax = ax*di + bv.x; ay = ay*di + bv.y;
  size_t o = (size_t)i*64 + lane;
  if (mode == 0) {
    outb[o] = cvt_pk_bf16(leakyf(ax), leakyf(ay));
  } else {
    float2 rs = ((const float2*)resid)[o];
    float vx = rs.x + ax, vy = rs.y + ay;
    float2 r; r.x = vx; r.y = vy;
    ((float2*)outf)[o] = r;
    if (ph) {
      unsigned ux = __float_as_uint(vx), uy = __float_as_uint(vy);
      ph[o] = pack_hi16(ux, uy);
      pl[o] = cvt_pk_bf16(vx - __uint_as_float(ux & 0xffff0000u),
                          vy - __uint_as_float(uy & 0xffff0000u));
    }
  }
}

// ---------------------------------------------------------------------------
// Graph setup
// ---------------------------------------------------------------------------
__global__ void count_kernel(const int* __restrict__ src, const int* __restrict__ dst,
                             int* __restrict__ cnt_src, int* __restrict__ deg_dst)
{
  int e = blockIdx.x*blockDim.x + threadIdx.x;
  if (e < NE) {
    atomicAdd(&cnt_src[src[e]], 1);
    atomicAdd(&deg_dst[dst[e]], 1);
  }
}

// two independent single-block scans; also folds nodeparams:
// block 0: deg -> rowptr,nextp + dis = rsqrt(deg+1)
// block 1: cnt -> srow,nexts   + invcnt = 1/max(cnt,1)
__global__ void scan2_kernel(const int* __restrict__ a0, int* __restrict__ r0, int* __restrict__ n0,
                             float* __restrict__ aux0,
                             const int* __restrict__ a1, int* __restrict__ r1, int* __restrict__ n1,
                             float* __restrict__ aux1)
{
  const int* a = blockIdx.x ? a1 : a0;
  int* r = blockIdx.x ? r1 : r0;
  int* n = blockIdx.x ? n1 : n0;
  float* aux = blockIdx.x ? aux1 : aux0;
  const int T = 256;
  int tid = threadIdx.x;
  int chunk = (NN + T - 1) / T;
  int begin = tid*chunk, end = begin + chunk; if (end > NN) end = NN; if (begin > NN) begin = NN;
  int s = 0;
  for (int i = begin; i < end; i++) s += a[i];
  __shared__ int ps[T];
  ps[tid] = s; __syncthreads();
  for (int off = 1; off < T; off <<= 1) {
    int v = 0;
    if (tid >= off) v = ps[tid - off];
    __syncthreads();
    if (tid >= off) ps[tid] += v;
    __syncthreads();
  }
  int base = (tid == 0) ? 0 : ps[tid-1];
  for (int i = begin; i < end; i++) {
    r[i] = base; n[i] = base; base += a[i];
    aux[i] = blockIdx.x ? (1.0f / fmaxf((float)a[i], 1.0f)) : rsqrtf((float)a[i] + 1.0f);
  }
  if (tid == T-1) r[NN] = base;
}

// fused CSR fill + src-sort fill (one pass over the edge list)
__global__ void fill_both_kernel(const int* __restrict__ src, const int* __restrict__ dst,
                                 int* __restrict__ nextp, int* __restrict__ csr_src,
                                 int* __restrict__ nexts, int* __restrict__ eperm,
                                 int* __restrict__ srcsorted)
{
  int e = blockIdx.x*blockDim.x + threadIdx.x;
  if (e < NE) {
    int s = src[e];
    int pos = atomicAdd(&nextp[dst[e]], 1);
    csr_src[pos] = s;
    int ps = atomicAdd(&nexts[s], 1);
    eperm[ps] = e;
    srcsorted[ps] = s;
  }
}

// ---------------------------------------------------------------------------
// BatchNorm stats (bf16 y) — dword loads (2 cols/thread), 4-row groups.
// ---------------------------------------------------------------------------
__global__ __launch_bounds__(256)
void bn_stats_kernel(const unsigned* __restrict__ yb32, float* __restrict__ sums)
{
  int cp  = threadIdx.x & 63;   // col pair 0..63
  int grp = threadIdx.x >> 6;   // 0..3
  float s0=0.f, s1=0.f, q0=0.f, q1=0.f;
  for (int i = blockIdx.x*4 + grp; i < NN; i += gridDim.x*4) {
    unsigned v = yb32[(size_t)i*64 + cp];
    float a = __uint_as_float(v << 16);
    float b = __uint_as_float(v & 0xffff0000u);
    s0 += a; q0 += a*a; s1 += b; q1 += b*b;
  }
  __shared__ float red[256][4];
  red[threadIdx.x][0]=s0; red[threadIdx.x][1]=s1; red[threadIdx.x][2]=q0; red[threadIdx.x][3]=q1;
  __syncthreads();
  if (grp == 0) {
    float t0=0.f,t1=0.f,t2=0.f,t3=0.f;
    #pragma unroll
    for (int g2=0; g2<4; g2++) {
      t0+=red[g2*64+cp][0]; t1+=red[g2*64+cp][1]; t2+=red[g2*64+cp][2]; t3+=red[g2*64+cp][3];
    }
    atomicAdd(&sums[2*cp],      t0);
    atomicAdd(&sums[2*cp+1],    t1);
    atomicAdd(&sums[DD+2*cp],   t2);
    atomicAdd(&sums[DD+2*cp+1], t3);
  }
}

// grid = 16 blocks; block b handles k in [b*8, b*8+8). cvec pre-zeroed.
__global__ __launch_bounds__(256)
void bn_fold_kernel(const float* __restrict__ sums, const float* __restrict__ g,
                    const float* __restrict__ b, const float* __restrict__ W2,
                    short* __restrict__ Wfh, short* __restrict__ Wfl,
                    float* __restrict__ cvec)
{
  __shared__ float scale_s[DD], shift_s[DD];
  int tid = threadIdx.x;
  if (tid < DD) {
    float m = sums[tid] / (float)NN;
    float var = sums[DD + tid] / (float)NN - m*m;
    float is = rsqrtf(var + LN_EPS);
    float sc = is * g[tid];
    scale_s[tid] = sc;
    shift_s[tid] = b[tid] - m * sc;
  }
  __syncthreads();
  int col = tid & 127, kh = tid >> 7;   // kh = 0..1
  float cpart = 0.f;
  #pragma unroll
  for (int kk = 0; kk < 4; kk++) {
    int k = blockIdx.x*8 + kh*4 + kk;
    float w = W2[k*DD + col];
    short2 t = f2bf2v(w * scale_s[k]);
    size_t o = ((size_t)(k >> 3)*128 + col)*8 + (k & 7);
    Wfh[o] = t.x; Wfl[o] = t.y;
    cpart += shift_s[k] * w;
  }
  atomicAdd(&cvec[col], cpart);
}

// ---------------------------------------------------------------------------
extern "C" void kernel_launch(void* const* d_in, const int* in_sizes, int n_in,
                              void* d_out, int out_size, void* d_ws, size_t ws_size,
                              hipStream_t stream)
{
  const float* node_feat = (const float*)d_in[0];
  const float* edge_feat = (const float*)d_in[1];
  const int*   edge_index = (const int*)d_in[2];
  const int* src = edge_index;
  const int* dst = edge_index + NE;

  const float* enW1 = (const float*)d_in[3];  const float* enb1 = (const float*)d_in[4];
  const float* enW2 = (const float*)d_in[5];  const float* enb2 = (const float*)d_in[6];
  const float* enW3 = (const float*)d_in[7];  const float* enb3 = (const float*)d_in[8];
  const float* enlg = (const float*)d_in[9];  const float* enlb = (const float*)d_in[10];

  const float* eeW1 = (const float*)d_in[11]; const float* eeb1 = (const float*)d_in[12];
  const float* eeW2 = (const float*)d_in[13]; const float* eeb2 = (const float*)d_in[14];
  const float* eeW3 = (const float*)d_in[15]; const float* eeb3 = (const float*)d_in[16];
  const float* eelg = (const float*)d_in[17]; const float* eelb = (const float*)d_in[18];

  const float* procW = (const float*)d_in[19];
  const float* procB = (const float*)d_in[20];
  const float* bnG   = (const float*)d_in[21];
  const float* bnB   = (const float*)d_in[22];

  const float* dW1 = (const float*)d_in[23]; const float* db1 = (const float*)d_in[24];
  const float* dW2 = (const float*)d_in[25]; const float* db2 = (const float*)d_in[26];
  const float* dW3 = (const float*)d_in[27]; const float* db3 = (const float*)d_in[28];
  const float* dlg = (const float*)d_in[29]; const float* dlb = (const float*)d_in[30];

  char* ws = (char*)d_ws;
  size_t off = 0;
  auto alloc = [&](size_t bytes) -> void* {
    void* p = ws + off;
    off = (off + bytes + 255) & ~(size_t)255;
    return p;
  };
  float* hn     = (float*)alloc((size_t)NN*DD*4);
  unsigned short* hbf = (unsigned short*)alloc((size_t)NN*DD*2);  // bf16 gather table
  unsigned short* ybf = (unsigned short*)alloc((size_t)NN*DD*2);  // bf16 y (BN input)
  unsigned* hnh = (unsigned*)alloc((size_t)NN*DD/2*4);  // hn hi-plane (bf16 pairs)
  unsigned* hnl = (unsigned*)alloc((size_t)NN*DD/2*4);  // hn lo-plane (bf16 pairs)
  float* dis    = (float*)alloc(NN*4);
  float* invcnt = (float*)alloc(NN*4);
  float* bnsums5 = (float*)alloc(5*3*DD*4);  // 5 steps x [sum, sumsq, cvec]
  int* deg    = (int*)alloc(NN*4);
  int* cnt    = (int*)alloc(NN*4);
  int* rowptr = (int*)alloc((NN+1)*4);
  int* nextp  = (int*)alloc(NN*4);
  int* srow   = (int*)alloc((NN+1)*4);
  int* nexts  = (int*)alloc(NN*4);
  int* csr    = (int*)alloc((size_t)NE*4);
  int* eperm  = (int*)alloc((size_t)NE*4);
  int* srcsorted = (int*)alloc((size_t)NE*4);
  auto allocW = [&](int kp) { return (short*)alloc((size_t)kp*128*2); };
  short *pN1h=allocW(32),  *pN1l=allocW(32);
  short *pN2h=allocW(128), *pN2l=allocW(128);
  short *pN3h=allocW(128), *pN3l=allocW(128);
  short *pE1h=allocW(32),  *pE1l=allocW(32);
  short *pE2h=allocW(128), *pE2l=allocW(128);
  short *pE3h=allocW(128), *pE3l=allocW(128);
  short *pD1h=allocW(128), *pD1l=allocW(128);
  short *pD2h=allocW(128), *pD2l=allocW(128);
  short *pD3h=allocW(128), *pD3l=allocW(128);
  short *pP0h[5], *pP0l[5];
  for (int s = 0; s < 5; s++) { pP0h[s]=allocW(128); pP0l[s]=allocW(128); }
  short *pWfh=allocW(128), *pWfl=allocW(128);

  (void)hipMemsetAsync(deg, 0, NN*4, stream);
  (void)hipMemsetAsync(cnt, 0, NN*4, stream);
  (void)hipMemsetAsync(bnsums5, 0, 5*3*DD*4, stream);

  // pack static weights: 12 K=128 mats in one launch + 1 small 2D launch
  PackArgs pa;
  const float* s128[NPACK] = { enW2, enW3, eeW2, eeW3, dW1, dW2, dW3,
                               procW + 0*(size_t)DD*DD*2, procW + 1*(size_t)DD*DD*2,
                               procW + 2*(size_t)DD*DD*2, procW + 3*(size_t)DD*DD*2,
                               procW + 4*(size_t)DD*DD*2 };
  short* d128h[NPACK] = { pN2h, pN3h, pE2h, pE3h, pD1h, pD2h, pD3h,
                          pP0h[0], pP0h[1], pP0h[2], pP0h[3], pP0h[4] };
  short* d128l[NPACK] = { pN2l, pN3l, pE2l, pE3l, pD1l, pD2l, pD3l,
                          pP0l[0], pP0l[1], pP0l[2], pP0l[3], pP0l[4] };
  for (int m = 0; m < NPACK; m++) { pa.src[m]=s128[m]; pa.dh[m]=d128h[m]; pa.dl[m]=d128l[m]; }
  pack_many_kernel<<<dim3(64, NPACK), 256, 0, stream>>>(pa);
  pack_small_kernel<<<dim3(16, 2), 256, 0, stream>>>(enW1, pN1h, pN1l, eeW1, eeb1, pE1h);

  // graph setup
  count_kernel<<<(NE+255)/256, 256, 0, stream>>>(src, dst, cnt, deg);
  scan2_kernel<<<2, 256, 0, stream>>>(deg, rowptr, nextp, dis, cnt, srow, nexts, invcnt);
  fill_both_kernel<<<(NE+255)/256, 256, 0, stream>>>(src, dst, nextp, csr, nexts, eperm, srcsorted);

  const int GN  = (NN + 127) / 128;  // 391
  const int GE  = NE / 128;          // 6250
  const int GG  = (NN + 63) / 64;    // 782
  const int GA  = (NN + 3) / 4;      // 12500

  // encoders: node MLP writes hn, edge MLP atomically adds scatter-mean into hn
  mlp_mfma_kernel<19, false><<<GN, 256, 0, stream>>>(node_feat, NN,
      pN1h, pN1l, enb1, pN2h, pN2l, enb2, pN3h, pN3l, enb3, enlg, enlb, hn,
      nullptr, nullptr, nullptr);
  mlp_mfma_kernel<4, true><<<GE, 256, 0, stream>>>(edge_feat, NE,
      pE1h, pE1l, eeb1, pE2h, pE2l, eeb2, pE3h, pE3l, eeb3, eelg, eelb, hn,
      srcsorted, eperm, invcnt);

  // processor: 5 residual (conv -> leaky -> BN -> conv) steps
  for (int s = 0; s < 5; s++) {
    const float* Wc2 = procW + (size_t)(s*2+1)*DD*DD;
    const float* b0  = procB + (size_t)(s*2+0)*DD;
    const float* b1p = procB + (size_t)(s*2+1)*DD;
    float* sums = bnsums5 + (size_t)s*3*DD;
    float* cvec = sums + 2*DD;

    if (s == 0)
      gemm_mfma_kernel<<<GG, 256, 0, stream>>>(hn, pP0h[s], pP0l[s], nullptr, dis, hbf, NN);
    else
      gemm_pl_mfma_kernel<<<GG, 256, 0, stream>>>((const unsigned short*)hnh,
          (const unsigned short*)hnl, pP0h[s], pP0l[s], nullptr, dis, hbf, NN);
    gcn_agg_kernel<<<GA, 256, 0, stream>>>((const unsigned*)hbf, rowptr, csr, dis,
                                           b0, nullptr, nullptr, (unsigned*)ybf,
                                           nullptr, nullptr, 0);
    bn_stats_kernel<<<512, 256, 0, stream>>>((const unsigned*)ybf, sums);
    bn_fold_kernel<<<16, 256, 0, stream>>>(sums, bnG + s*DD, bnB + s*DD, Wc2, pWfh, pWfl, cvec);
    gemm_bf_mfma_kernel<<<GG, 256, 0, stream>>>(ybf, pWfh, pWfl, cvec, dis, hbf, NN);
    gcn_agg_kernel<<<GA, 256, 0, stream>>>((const unsigned*)hbf, rowptr, csr, dis,
                                           b1p, hn, hn, nullptr,
                                           (s < 4) ? hnh : nullptr,
                                           (s < 4) ? hnl : nullptr, 1);
  }

  // decoder -> d_out (fp32)
  mlp_mfma_kernel<128, false><<<GN, 256, 0, stream>>>(hn, NN,
      pD1h, pD1l, db1, pD2h, pD2l, db2, pD3h, pD3l, db3, dlg, dlb, (float*)d_out,
      nullptr, nullptr, nullptr);
}

// Round 7
// 1249.302 us; speedup vs baseline: 1.2169x; 1.0950x over previous
//
#include <hip/hip_runtime.h>

#define NN 50000
#define NE 800000
#define DD 128
#define LN_EPS 1e-5f
#define NSLICE 64
#define SLSTRIDE (NSLICE*256 + DD)   // per-step: 64 slices x [s(128)|q(128)] + cvec(128)

typedef __attribute__((ext_vector_type(8))) short v8s;    // 8 bf16
typedef __attribute__((ext_vector_type(4))) unsigned v4u; // same 16B as v8s
typedef __attribute__((ext_vector_type(4))) float f32x4;  // MFMA acc
typedef __attribute__((ext_vector_type(2))) float f32x2;  // packed-f32 pair

union CvtHL { v4u u; v8s s; };

__device__ __forceinline__ float leakyf(float x){ return x > 0.f ? x : 0.05f*x; }
__device__ __forceinline__ short f2bf(float f){
  unsigned u = __float_as_uint(f);
  u = (u + 0x7fffu + ((u >> 16) & 1u)) >> 16;   // RNE
  return (short)u;
}
__device__ __forceinline__ float bf2f(unsigned short h){
  return __uint_as_float(((unsigned)h) << 16);
}
// HW RNE pack: low16 = bf16(a), high16 = bf16(b). 1 inst for 2 values.
__device__ __forceinline__ unsigned cvt_pk_bf16(float a, float b){
  unsigned r;
  asm("v_cvt_pk_bf16_f32 %0, %1, %2" : "=v"(r) : "v"(a), "v"(b));
  return r;
}
// packed f32 math (CDNA VOP3P): 2 floats / instruction
__device__ __forceinline__ f32x2 pk_add(f32x2 a, f32x2 b){
  f32x2 r; asm("v_pk_add_f32 %0, %1, %2" : "=v"(r) : "v"(a), "v"(b)); return r;
}
__device__ __forceinline__ f32x2 pk_mul(f32x2 a, f32x2 b){
  f32x2 r; asm("v_pk_mul_f32 %0, %1, %2" : "=v"(r) : "v"(a), "v"(b)); return r;
}
// [hi16(u0) | hi16(u1)<<16] in one v_perm_b32
__device__ __forceinline__ unsigned pack_hi16(unsigned u0, unsigned u1){
  return __builtin_amdgcn_perm(u1, u0, 0x07060302u);
}
// split fp32 -> {hi, lo}: hi = truncated top-16 (cheap), lo = RNE(residual).
__device__ __forceinline__ short2 f2bf2v(float v){
  unsigned u = __float_as_uint(v);
  short hi = (short)(u >> 16);
  float lo = v - __uint_as_float(u & 0xffff0000u);
  return make_short2(hi, f2bf(lo));
}

// ---------------------------------------------------------------------------
// Weight packing. Layout: [(k>>3)*128+n][k&7] hi/lo bf16 planes.
// pack_small: y=0 node-encoder W1 (K=19 padded to 32) -> hi/lo planes;
//             y=1 edge-encoder W1+b1 folded single plane (see below).
// ---------------------------------------------------------------------------
__global__ void pack_small_kernel(const float* __restrict__ nW1,
                                  short* __restrict__ nWh, short* __restrict__ nWl,
                                  const float* __restrict__ eW1, const float* __restrict__ eb1,
                                  short* __restrict__ eWp)
{
  int idx = blockIdx.x*256 + threadIdx.x;   // 0..4095
  int k = idx >> 7, n = idx & 127;
  size_t o = ((size_t)(k >> 3)*128 + n)*8 + (k & 7);
  if (blockIdx.y == 0) {
    float v = (k < 19) ? nW1[k*128 + n] : 0.f;
    short2 t = f2bf2v(v);
    nWh[o] = t.x; nWl[o] = t.y;
  } else {
    // rows 0-3: hi(W1) (pairs A=xh); 4-7: lo(W1) (A=xh); 8-11: hi(W1) (A=xl);
    // 12: hi(b1), 13: lo(b1) (A=1.0); rest 0. One MFMA = xh@Wh+xh@Wl+xl@Wh+b1.
    short v = 0;
    if (k < 4)        v = f2bf2v(eW1[k*128 + n]).x;
    else if (k < 8)   v = f2bf2v(eW1[(k-4)*128 + n]).y;
    else if (k < 12)  v = f2bf2v(eW1[(k-8)*128 + n]).x;
    else if (k == 12) v = f2bf2v(eb1[n]).x;
    else if (k == 13) v = f2bf2v(eb1[n]).y;
    eWp[o] = v;
  }
}

#define NPACK 12
struct PackArgs { const float* src[NPACK]; short* dh[NPACK]; short* dl[NPACK]; };

// all-K=128 batch pack: grid (64, NPACK)
__global__ void pack_many_kernel(PackArgs pa)
{
  int m = blockIdx.y;
  int idx = blockIdx.x*256 + threadIdx.x;   // 0..16383
  int k = idx >> 7, n = idx & 127;
  float v = pa.src[m][k*128 + n];
  short2 t = f2bf2v(v);
  size_t o = ((size_t)(k >> 3)*128 + n)*8 + (k & 7);
  pa.dh[m][o] = t.x; pa.dl[m][o] = t.y;
}

// full split-split product (A has hi+lo)
#define MFMA3(ah, al, bh, bl, ac) \
  ac = __builtin_amdgcn_mfma_f32_16x16x32_bf16(al, bh, ac, 0,0,0); \
  ac = __builtin_amdgcn_mfma_f32_16x16x32_bf16(ah, bl, ac, 0,0,0); \
  ac = __builtin_amdgcn_mfma_f32_16x16x32_bf16(ah, bh, ac, 0,0,0);

// A exact-bf16 (no lo plane): 2 MFMAs
#define MFMA2(ah, bh, bl, ac) \
  ac = __builtin_amdgcn_mfma_f32_16x16x32_bf16(ah, bl, ac, 0,0,0); \
  ac = __builtin_amdgcn_mfma_f32_16x16x32_bf16(ah, bh, ac, 0,0,0);

// 8 fp32 -> hi-plane (v_perm pack) + lo-plane (cvt_pk RNE)
#define SPLIT8(f0, f1, h, l) { \
  unsigned u0=__float_as_uint(f0.x), u1=__float_as_uint(f0.y), u2=__float_as_uint(f0.z), u3=__float_as_uint(f0.w); \
  unsigned u4=__float_as_uint(f1.x), u5=__float_as_uint(f1.y), u6=__float_as_uint(f1.z), u7=__float_as_uint(f1.w); \
  CvtHL ch_, cl_; \
  ch_.u = (v4u){ pack_hi16(u0,u1), pack_hi16(u2,u3), pack_hi16(u4,u5), pack_hi16(u6,u7) }; \
  cl_.u = (v4u){ \
    cvt_pk_bf16(f0.x-__uint_as_float(u0&0xffff0000u), f0.y-__uint_as_float(u1&0xffff0000u)), \
    cvt_pk_bf16(f0.z-__uint_as_float(u2&0xffff0000u), f0.w-__uint_as_float(u3&0xffff0000u)), \
    cvt_pk_bf16(f1.x-__uint_as_float(u4&0xffff0000u), f1.y-__uint_as_float(u5&0xffff0000u)), \
    cvt_pk_bf16(f1.z-__uint_as_float(u6&0xffff0000u), f1.w-__uint_as_float(u7&0xffff0000u)) }; \
  h = ch_.s; l = cl_.s; }

// bias + leaky + bf16-pack on paired acc halves. Bit-identical to the scalar
// version: x=acc+bv (pk_add), m=0.05*x (pk_mul), max, HW-RNE cvt.
#define EPI_PK(accv, bv2, DOBIAS, p01, p23) { \
  f32x2 x01 = (f32x2){(accv)[0], (accv)[1]}; \
  f32x2 x23 = (f32x2){(accv)[2], (accv)[3]}; \
  if (DOBIAS) { x01 = pk_add(x01, bv2); x23 = pk_add(x23, bv2); } \
  f32x2 m01 = pk_mul(x01, (f32x2)(0.05f)); \
  f32x2 m23 = pk_mul(x23, (f32x2)(0.05f)); \
  p01 = cvt_pk_bf16(fmaxf(x01.x, m01.x), fmaxf(x01.y, m01.y)); \
  p23 = cvt_pk_bf16(fmaxf(x23.x, m23.x), fmaxf(x23.y, m23.y)); }

// ---------------------------------------------------------------------------
// 3-layer MLP + LayerNorm. Layer-1 inputs and all weights hi/lo split;
// hidden activations single-bf16 (layers 2/3 use 2 MFMAs).
// SCATTER (edge): layer-1 uses the single-plane combined weight (1 MFMA/tile,
// bias folded into K); LN stats use a shared reduce-scatter butterfly;
// seg-reduce flushes are pre-scaled by invcnt[src] and land directly in hn
// (scatter-MEAN fused -> no esum buffer / memset / addmean pass).
// ---------------------------------------------------------------------------
template<int IN_W, bool SCATTER>
__global__ __launch_bounds__(256)
void mlp_mfma_kernel(const float* __restrict__ x, int nrows,
                     const short* __restrict__ W1h, const short* __restrict__ W1l,
                     const float* __restrict__ b1,
                     const short* __restrict__ W2h, const short* __restrict__ W2l,
                     const float* __restrict__ b2,
                     const short* __restrict__ W3h, const short* __restrict__ W3l,
                     const float* __restrict__ b3,
                     const float* __restrict__ g, const float* __restrict__ bb,
                     float* __restrict__ out,
                     const int* __restrict__ sidx,   // src-sorted src values
                     const int* __restrict__ eperm,  // sorted pos -> edge id
                     const float* __restrict__ invcnt) // 1/max(cnt,1) per node
{
  constexpr int L1K = (IN_W + 31) / 32;
  constexpr bool EDGE1 = (SCATTER && IN_W == 4);
  __shared__ __align__(16) short Hh[128*136];   // act plane; reused (stride 132) as bf16 seg buffer
  __shared__ float lnS[128][2], lnQ[128][2];
  __shared__ int sidx_s[128];
  __shared__ __align__(16) uint4 xstage[SCATTER ? 128 : 1];  // pre-split hi/lo packs

  const int tid  = threadIdx.x;
  const int lane = tid & 63, wave = tid >> 6;
  const int wr = wave >> 1, wc = wave & 1;
  const int quad = lane >> 4, low = lane & 15;
  const int row0 = blockIdx.x * 128;

  if (SCATTER) {
    // 128 parallel scattered gathers + hi/lo split -> LDS stage
    if (tid < 128) {
      int e = eperm[row0 + tid];           // NE % 128 == 0
      float4 f = ((const float4*)x)[e];
      unsigned u0=__float_as_uint(f.x), u1=__float_as_uint(f.y);
      unsigned u2=__float_as_uint(f.z), u3=__float_as_uint(f.w);
      uint4 st;
      st.x = pack_hi16(u0,u1);
      st.y = pack_hi16(u2,u3);
      st.z = cvt_pk_bf16(f.x-__uint_as_float(u0&0xffff0000u), f.y-__uint_as_float(u1&0xffff0000u));
      st.w = cvt_pk_bf16(f.z-__uint_as_float(u2&0xffff0000u), f.w-__uint_as_float(u3&0xffff0000u));
      xstage[tid] = st;
      sidx_s[tid] = sidx[row0 + tid];
    }
    __syncthreads();
  }

  f32x4 acc[4][4];

  // ---------------- layer 1 ----------------
  #pragma unroll
  for (int tm=0;tm<4;tm++)
    #pragma unroll
    for (int tn=0;tn<4;tn++) acc[tm][tn] = (f32x4)0.f;

  if constexpr (EDGE1) {
    // single-plane: K slots 0-7 = xh (pairs Wh,Wl rows), 8-11 = xl (pairs Wh),
    // 12-13 = 1.0 (pairs b1 hi/lo rows). One MFMA per tile.
    v8s ah[4], bh[4];
    #pragma unroll
    for (int tm=0;tm<4;tm++) {
      int lr = wr*64 + tm*16 + low;
      v8s h = (v8s)0;
      if (quad == 0) {
        uint4 st = xstage[lr];
        CvtHL c_; c_.u = (v4u){ st.x, st.y, st.x, st.y };
        h = c_.s;
      } else if (quad == 1) {
        uint4 st = xstage[lr];
        CvtHL c_; c_.u = (v4u){ st.z, st.w, 0x3F803F80u, 0u };
        h = c_.s;
      }
      ah[tm] = h;
    }
    #pragma unroll
    for (int tn=0;tn<4;tn++) {
      size_t o = ((size_t)quad*128 + wc*64 + tn*16 + low)*8;
      bh[tn] = *(const v8s*)(W1h + o);
    }
    #pragma unroll
    for (int tm=0;tm<4;tm++)
      #pragma unroll
      for (int tn=0;tn<4;tn++)
        acc[tm][tn] = __builtin_amdgcn_mfma_f32_16x16x32_bf16(ah[tm], bh[tn], acc[tm][tn], 0,0,0);
  } else {
    for (int ks = 0; ks < L1K; ks++) {
      v8s ah[4], al[4], bh[4], bl[4];
      #pragma unroll
      for (int tm=0;tm<4;tm++) {
        int lr = wr*64 + tm*16 + low;
        v8s h = (v8s)0, l = (v8s)0;
        if (IN_W % 32 == 0) {
          int r = row0 + lr;
          if (r < nrows) {
            const float* p = x + (size_t)r*IN_W + ks*32 + quad*8;
            float4 f0 = *(const float4*)p;
            float4 f1 = *(const float4*)(p + 4);
            SPLIT8(f0, f1, h, l);
          }
        } else {
          int r = row0 + lr;
          #pragma unroll
          for (int j=0;j<8;j++) {
            int k = ks*32 + quad*8 + j;
            if (k < IN_W && r < nrows) {
              short2 t = f2bf2v(x[(size_t)r*IN_W + k]);
              h[j] = t.x; l[j] = t.y;
            }
          }
        }
        ah[tm] = h; al[tm] = l;
      }
      #pragma unroll
      for (int tn=0;tn<4;tn++) {
        size_t o = ((size_t)(ks*4+quad)*128 + wc*64 + tn*16 + low)*8;
        bh[tn] = *(const v8s*)(W1h + o);
        bl[tn] = *(const v8s*)(W1l + o);
      }
      #pragma unroll
      for (int tm=0;tm<4;tm++)
        #pragma unroll
        for (int tn=0;tn<4;tn++) { MFMA3(ah[tm], al[tm], bh[tn], bl[tn], acc[tm][tn]); }
    }
  }
  #pragma unroll
  for (int tn=0;tn<4;tn++) {
    float bv = EDGE1 ? 0.f : b1[wc*64 + tn*16 + low];
    f32x2 bv2 = (f32x2)(bv);
    #pragma unroll
    for (int tm=0;tm<4;tm++) {
      unsigned p01, p23;
      EPI_PK(acc[tm][tn], bv2, !EDGE1, p01, p23);
      int base = (wr*64+tm*16+quad*4)*136 + wc*64+tn*16+low;
      Hh[base]     = (short)p01;
      Hh[base+136] = (short)(p01>>16);
      Hh[base+272] = (short)p23;
      Hh[base+408] = (short)(p23>>16);
    }
  }
  __syncthreads();

  // ---------------- layer 2 (bf16 A from LDS, 2 MFMAs) ----------------
  #pragma unroll
  for (int tm=0;tm<4;tm++)
    #pragma unroll
    for (int tn=0;tn<4;tn++) acc[tm][tn] = (f32x4)0.f;
  #pragma unroll
  for (int ks=0;ks<4;ks++) {
    v8s ah[4], bh[4], bl[4];
    #pragma unroll
    for (int tm=0;tm<4;tm++)
      ah[tm] = *(const v8s*)&Hh[(wr*64+tm*16+low)*136 + ks*32 + quad*8];
    #pragma unroll
    for (int tn=0;tn<4;tn++) {
      size_t o = ((size_t)(ks*4+quad)*128 + wc*64 + tn*16 + low)*8;
      bh[tn] = *(const v8s*)(W2h + o);
      bl[tn] = *(const v8s*)(W2l + o);
    }
    #pragma unroll
    for (int tm=0;tm<4;tm++)
      #pragma unroll
      for (int tn=0;tn<4;tn++) { MFMA2(ah[tm], bh[tn], bl[tn], acc[tm][tn]); }
  }
  __syncthreads();
  #pragma unroll
  for (int tn=0;tn<4;tn++) {
    float bv = b2[wc*64 + tn*16 + low];
    f32x2 bv2 = (f32x2)(bv);
    #pragma unroll
    for (int tm=0;tm<4;tm++) {
      unsigned p01, p23;
      EPI_PK(acc[tm][tn], bv2, true, p01, p23);
      int base = (wr*64+tm*16+quad*4)*136 + wc*64+tn*16+low;
      Hh[base]     = (short)p01;
      Hh[base+136] = (short)(p01>>16);
      Hh[base+272] = (short)p23;
      Hh[base+408] = (short)(p23>>16);
    }
  }
  __syncthreads();

  // ---------------- layer 3 (bf16 A from LDS, 2 MFMAs) ----------------
  #pragma unroll
  for (int tm=0;tm<4;tm++)
    #pragma unroll
    for (int tn=0;tn<4;tn++) acc[tm][tn] = (f32x4)0.f;
  #pragma unroll
  for (int ks=0;ks<4;ks++) {
    v8s ah[4], bh[4], bl[4];
    #pragma unroll
    for (int tm=0;tm<4;tm++)
      ah[tm] = *(const v8s*)&Hh[(wr*64+tm*16+low)*136 + ks*32 + quad*8];
    #pragma unroll
    for (int tn=0;tn<4;tn++) {
      size_t o = ((size_t)(ks*4+quad)*128 + wc*64 + tn*16 + low)*8;
      bh[tn] = *(const v8s*)(W3h + o);
      bl[tn] = *(const v8s*)(W3l + o);
    }
    #pragma unroll
    for (int tm=0;tm<4;tm++)
      #pragma unroll
      for (int tn=0;tn<4;tn++) { MFMA2(ah[tm], bh[tn], bl[tn], acc[tm][tn]); }
  }
  #pragma unroll
  for (int tn=0;tn<4;tn++) {
    float bv = b3[wc*64 + tn*16 + low];
    #pragma unroll
    for (int tm=0;tm<4;tm++)
      #pragma unroll
      for (int i=0;i<4;i++) acc[tm][tn][i] += bv;
  }

  // ---------------- fused LayerNorm ----------------
  // Reduce-scatter butterfly: all 16 (tm,i) row-reductions share one 4-step
  // butterfly (masks 1,2,4,8 — identical tree association, bit-identical).
  {
    float ct[16];
    #pragma unroll
    for (int tm=0;tm<4;tm++)
      #pragma unroll
      for (int i=0;i<4;i++)
        ct[tm*4+i] = acc[tm][0][i] + acc[tm][1][i] + acc[tm][2][i] + acc[tm][3][i];
    #pragma unroll
    for (int st=0; st<4; st++) {
      const int mm = 1 << st;
      const bool hbit = ((low >> st) & 1) != 0;
      #pragma unroll
      for (int p=0; p < (16>>st); p+=2) {
        float snd = hbit ? ct[p]   : ct[p+1];
        float kp  = hbit ? ct[p+1] : ct[p];
        ct[p>>1] = kp + __shfl_xor(snd, mm);
      }
    }
    { int r = wr*64 + (low>>2)*16 + quad*4 + (low&3); lnS[r][wc] = ct[0]; }
    #pragma unroll
    for (int tm=0;tm<4;tm++)
      #pragma unroll
      for (int i=0;i<4;i++)
        ct[tm*4+i] = acc[tm][0][i]*acc[tm][0][i] + acc[tm][1][i]*acc[tm][1][i]
                   + acc[tm][2][i]*acc[tm][2][i] + acc[tm][3][i]*acc[tm][3][i];
    #pragma unroll
    for (int st=0; st<4; st++) {
      const int mm = 1 << st;
      const bool hbit = ((low >> st) & 1) != 0;
      #pragma unroll
      for (int p=0; p < (16>>st); p+=2) {
        float snd = hbit ? ct[p]   : ct[p+1];
        float kp  = hbit ? ct[p+1] : ct[p];
        ct[p>>1] = kp + __shfl_xor(snd, mm);
      }
    }
    { int r = wr*64 + (low>>2)*16 + quad*4 + (low&3); lnQ[r][wc] = ct[0]; }
  }
  __syncthreads();   // all layer-3 H reads done (act-plane reuse below is safe)

  float g4[4], bb4[4];
  #pragma unroll
  for (int tn=0;tn<4;tn++) { int c = wc*64+tn*16+low; g4[tn] = g[c]; bb4[tn] = bb[c]; }

  #pragma unroll
  for (int tm=0;tm<4;tm++)
    #pragma unroll
    for (int i=0;i<4;i++) {
      int r = wr*64 + tm*16 + quad*4 + i;
      float2 S2 = *(const float2*)&lnS[r][0];
      float2 Q2 = *(const float2*)&lnQ[r][0];
      float s = S2.x + S2.y;
      float q = Q2.x + Q2.y;
      float m = s * (1.f/128.f);
      float var = q * (1.f/128.f) - m*m;
      float rs = rsqrtf(var + LN_EPS);
      int gr = row0 + r;
      if (!SCATTER && gr >= nrows) continue;
      float v0 = (acc[tm][0][i] - m) * rs * g4[0] + bb4[0];
      float v1 = (acc[tm][1][i] - m) * rs * g4[1] + bb4[1];
      float v2 = (acc[tm][2][i] - m) * rs * g4[2] + bb4[2];
      float v3 = (acc[tm][3][i] - m) * rs * g4[3] + bb4[3];
      if (SCATTER) {
        unsigned p01 = cvt_pk_bf16(v0, v1), p23 = cvt_pk_bf16(v2, v3);
        int base = r*132 + wc*64 + low;
        Hh[base]    = (short)p01;      // bf16 stage for seg-reduce
        Hh[base+16] = (short)(p01>>16);
        Hh[base+32] = (short)p23;
        Hh[base+48] = (short)(p23>>16);
      } else {
        size_t ob = (size_t)gr*DD + wc*64 + low;
        out[ob]    = v0;
        out[ob+16] = v1;
        out[ob+32] = v2;
        out[ob+48] = v3;
      }
    }

  if (SCATTER) {
    __syncthreads();
    // dword-vectorized seg-reduce: wave g handles rows [g*32, g*32+32),
    // 64 col-pairs; flushes scaled by invcnt[cur] straight into hn.
    const unsigned* H32 = (const unsigned*)Hh;    // row stride 66 dwords
    int cp = tid & 63;
    int gI = tid >> 6;
    int rbeg = gI*32, rend = rbeg + 32;
    unsigned pv = H32[rbeg*66 + cp];
    float a0 = __uint_as_float(pv << 16), a1 = __uint_as_float(pv & 0xffff0000u);
    int cur = __builtin_amdgcn_readfirstlane(sidx_s[rbeg]);
    for (int r = rbeg + 1; r < rend; r++) {
      int sv = __builtin_amdgcn_readfirstlane(sidx_s[r]);   // wave-uniform scalar
      unsigned hv = H32[r*66 + cp];
      if (sv != cur) {
        float ic = invcnt[cur];
        atomicAdd(&out[(size_t)cur*DD + 2*cp],     a0*ic);
        atomicAdd(&out[(size_t)cur*DD + 2*cp + 1], a1*ic);
        a0 = __uint_as_float(hv << 16); a1 = __uint_as_float(hv & 0xffff0000u);
        cur = sv;
      } else {
        a0 += __uint_as_float(hv << 16); a1 += __uint_as_float(hv & 0xffff0000u);
      }
    }
    float ic = invcnt[cur];
    atomicAdd(&out[(size_t)cur*DD + 2*cp],     a0*ic);
    atomicAdd(&out[(size_t)cur*DD + 2*cp + 1], a1*ic);
  }
}

// ---------------------------------------------------------------------------
// outbf[r] = bf16((x[r] @ W + initv) * rowscale[r])  — fp32 input (split, 3 MFMA)
// ---------------------------------------------------------------------------
__global__ __launch_bounds__(256)
void gemm_mfma_kernel(const float* __restrict__ x,
                      const short* __restrict__ Wh, const short* __restrict__ Wl,
                      const float* __restrict__ initv, const float* __restrict__ rowscale,
                      unsigned short* __restrict__ outbf, int nrows)
{
  const int tid  = threadIdx.x;
  const int lane = tid & 63, wave = tid >> 6;
  const int wr = wave >> 1, wc = wave & 1;
  const int quad = lane >> 4, low = lane & 15;
  const int row0 = blockIdx.x * 64;

  f32x4 acc[2][4];
  #pragma unroll
  for (int tm=0;tm<2;tm++)
    #pragma unroll
    for (int tn=0;tn<4;tn++) acc[tm][tn] = (f32x4)0.f;

  #pragma unroll
  for (int ks=0;ks<4;ks++) {
    v8s ah[2], al[2], bh[4], bl[4];
    #pragma unroll
    for (int tm=0;tm<2;tm++) {
      int r = row0 + wr*32 + tm*16 + low;
      v8s h = (v8s)0, l = (v8s)0;
      if (r < nrows) {
        const float* p = x + (size_t)r*DD + ks*32 + quad*8;
        float4 f0 = *(const float4*)p;
        float4 f1 = *(const float4*)(p + 4);
        SPLIT8(f0, f1, h, l);
      }
      ah[tm] = h; al[tm] = l;
    }
    #pragma unroll
    for (int tn=0;tn<4;tn++) {
      size_t o = ((size_t)(ks*4+quad)*128 + wc*64 + tn*16 + low)*8;
      bh[tn] = *(const v8s*)(Wh + o);
      bl[tn] = *(const v8s*)(Wl + o);
    }
    #pragma unroll
    for (int tm=0;tm<2;tm++)
      #pragma unroll
      for (int tn=0;tn<4;tn++) { MFMA3(ah[tm], al[tm], bh[tn], bl[tn], acc[tm][tn]); }
  }

  float iv4[4];
  #pragma unroll
  for (int tn=0;tn<4;tn++) iv4[tn] = initv ? initv[wc*64 + tn*16 + low] : 0.f;

  #pragma unroll
  for (int tm=0;tm<2;tm++)
    #pragma unroll
    for (int i=0;i<4;i++) {
      int gr = row0 + wr*32 + tm*16 + quad*4 + i;
      if (gr >= nrows) continue;
      float sc = rowscale ? rowscale[gr] : 1.f;
      float v0 = (acc[tm][0][i] + iv4[0]) * sc;
      float v1 = (acc[tm][1][i] + iv4[1]) * sc;
      float v2 = (acc[tm][2][i] + iv4[2]) * sc;
      float v3 = (acc[tm][3][i] + iv4[3]) * sc;
      unsigned p01 = cvt_pk_bf16(v0, v1), p23 = cvt_pk_bf16(v2, v3);
      size_t base = (size_t)gr*DD + wc*64 + low;
      outbf[base]    = (unsigned short)p01;
      outbf[base+16] = (unsigned short)(p01>>16);
      outbf[base+32] = (unsigned short)p23;
      outbf[base+48] = (unsigned short)(p23>>16);
    }
}

// ---------------------------------------------------------------------------
// Same but bf16 input (exact, 2 MFMA, 16 B/lane A-loads) — conv2 on y.
// ---------------------------------------------------------------------------
__global__ __launch_bounds__(256)
void gemm_bf_mfma_kernel(const unsigned short* __restrict__ xb,
                         const short* __restrict__ Wh, const short* __restrict__ Wl,
                         const float* __restrict__ initv, const float* __restrict__ rowscale,
                         unsigned short* __restrict__ outbf, int nrows)
{
  const int tid  = threadIdx.x;
  const int lane = tid & 63, wave = tid >> 6;
  const int wr = wave >> 1, wc = wave & 1;
  const int quad = lane >> 4, low = lane & 15;
  const int row0 = blockIdx.x * 64;

  f32x4 acc[2][4];
  #pragma unroll
  for (int tm=0;tm<2;tm++)
    #pragma unroll
    for (int tn=0;tn<4;tn++) acc[tm][tn] = (f32x4)0.f;

  #pragma unroll
  for (int ks=0;ks<4;ks++) {
    v8s ah[2], bh[4], bl[4];
    #pragma unroll
    for (int tm=0;tm<2;tm++) {
      int r = row0 + wr*32 + tm*16 + low;
      ah[tm] = (r < nrows) ? *(const v8s*)(xb + (size_t)r*DD + ks*32 + quad*8) : (v8s)0;
    }
    #pragma unroll
    for (int tn=0;tn<4;tn++) {
      size_t o = ((size_t)(ks*4+quad)*128 + wc*64 + tn*16 + low)*8;
      bh[tn] = *(const v8s*)(Wh + o);
      bl[tn] = *(const v8s*)(Wl + o);
    }
    #pragma unroll
    for (int tm=0;tm<2;tm++)
      #pragma unroll
      for (int tn=0;tn<4;tn++) { MFMA2(ah[tm], bh[tn], bl[tn], acc[tm][tn]); }
  }

  float iv4[4];
  #pragma unroll
  for (int tn=0;tn<4;tn++) iv4[tn] = initv ? initv[wc*64 + tn*16 + low] : 0.f;

  #pragma unroll
  for (int tm=0;tm<2;tm++)
    #pragma unroll
    for (int i=0;i<4;i++) {
      int gr = row0 + wr*32 + tm*16 + quad*4 + i;
      if (gr >= nrows) continue;
      float sc = rowscale ? rowscale[gr] : 1.f;
      float v0 = (acc[tm][0][i] + iv4[0]) * sc;
      float v1 = (acc[tm][1][i] + iv4[1]) * sc;
      float v2 = (acc[tm][2][i] + iv4[2]) * sc;
      float v3 = (acc[tm][3][i] + iv4[3]) * sc;
      unsigned p01 = cvt_pk_bf16(v0, v1), p23 = cvt_pk_bf16(v2, v3);
      size_t base = (size_t)gr*DD + wc*64 + low;
      outbf[base]    = (unsigned short)p01;
      outbf[base+16] = (unsigned short)(p01>>16);
      outbf[base+32] = (unsigned short)p23;
      outbf[base+48] = (unsigned short)(p23>>16);
    }
}

// ---------------------------------------------------------------------------
// GCN aggregation on bf16-packed pre-scaled h. One wave per node; unroll 16/4.
// R1/R4-proven structure: 64 lanes x dword per edge-row -> 16 outstanding
// loads per lane. wave id via readfirstlane -> scalar CSR walk.
// mode 0: outb = bf16(leaky(agg)); BN column sums/sumsq FUSED: per-block LDS
//         reduce (4 waves -> 64 lanes) then atomics into 64-slice partials
//         (3.2M atomics over 16K addrs ~ 195/addr). Stats computed on the
//         ROUNDED bf16 values (same data the old bn_stats pass read).
// mode 1: outf = resid + agg (fp32)
// NN == gridDim.x*4 exactly -> no early return (block-wide barrier safe).
// ---------------------------------------------------------------------------
__global__ __launch_bounds__(256)
void gcn_agg_kernel(const unsigned* __restrict__ hb, const int* __restrict__ rowptr,
                    const int* __restrict__ csr_src, const float* __restrict__ dis,
                    const float* __restrict__ bias, const float* __restrict__ resid,
                    float* __restrict__ outf, unsigned* __restrict__ outb,
                    float* __restrict__ slsums, int mode)
{
  __shared__ float red[256][4];
  const int wv = __builtin_amdgcn_readfirstlane(threadIdx.x >> 6);
  const int lane = threadIdx.x & 63;
  const int i = blockIdx.x*4 + wv;   // always < NN (NN % 4 == 0, grid = NN/4)
  unsigned hv = hb[(size_t)i*64 + lane];
  float ax = bf2f((unsigned short)(hv & 0xffff)), ay = bf2f((unsigned short)(hv >> 16));
  const int beg = rowptr[i], end = rowptr[i+1];
  int j = beg;
  for (; j + 16 <= end; j += 16) {
    unsigned v[16];
    #pragma unroll
    for (int k=0;k<16;k++) v[k] = hb[(size_t)csr_src[j+k]*64 + lane];
    #pragma unroll
    for (int k=0;k<16;k++) {
      ax += bf2f((unsigned short)(v[k] & 0xffff));
      ay += bf2f((unsigned short)(v[k] >> 16));
    }
  }
  for (; j + 4 <= end; j += 4) {
    unsigned v[4];
    #pragma unroll
    for (int k=0;k<4;k++) v[k] = hb[(size_t)csr_src[j+k]*64 + lane];
    #pragma unroll
    for (int k=0;k<4;k++) {
      ax += bf2f((unsigned short)(v[k] & 0xffff));
      ay += bf2f((unsigned short)(v[k] >> 16));
    }
  }
  for (; j < end; j++) {
    unsigned v = hb[(size_t)csr_src[j]*64 + lane];
    ax += bf2f((unsigned short)(v & 0xffff));
    ay += bf2f((unsigned short)(v >> 16));
  }
  float di = dis[i];
  float2 bv = ((const float2*)bias)[lane];
  ax = ax*di + bv.x; ay = ay*di + bv.y;
  size_t o = (size_t)i*64 + lane;
  if (mode == 0) {
    unsigned pk = cvt_pk_bf16(leakyf(ax), leakyf(ay));
    outb[o] = pk;
    // fused BN stats on the rounded bf16 values
    float a = bf2f((unsigned short)(pk & 0xffff));
    float b = bf2f((unsigned short)(pk >> 16));
    red[threadIdx.x][0] = a;   red[threadIdx.x][1] = b;
    red[threadIdx.x][2] = a*a; red[threadIdx.x][3] = b*b;
    __syncthreads();
    if (threadIdx.x < 64) {
      int l = threadIdx.x;
      float t0 = red[l][0] + red[64+l][0] + red[128+l][0] + red[192+l][0];
      float t1 = red[l][1] + red[64+l][1] + red[128+l][1] + red[192+l][1];
      float t2 = red[l][2] + red[64+l][2] + red[128+l][2] + red[192+l][2];
      float t3 = red[l][3] + red[64+l][3] + red[128+l][3] + red[192+l][3];
      float* S = slsums + (size_t)(blockIdx.x & (NSLICE-1))*256;
      atomicAdd(&S[2*l],       t0);
      atomicAdd(&S[2*l+1],     t1);
      atomicAdd(&S[128+2*l],   t2);
      atomicAdd(&S[128+2*l+1], t3);
    }
  } else {
    float2 rs = ((const float2*)resid)[o];
    float2 r; r.x = rs.x + ax; r.y = rs.y + ay;
    ((float2*)outf)[o] = r;
  }
}

// ---------------------------------------------------------------------------
// Graph setup
// ---------------------------------------------------------------------------
__global__ void count_kernel(const int* __restrict__ src, const int* __restrict__ dst,
                             int* __restrict__ cnt_src, int* __restrict__ deg_dst)
{
  int e = blockIdx.x*blockDim.x + threadIdx.x;
  if (e < NE) {
    atomicAdd(&cnt_src[src[e]], 1);
    atomicAdd(&deg_dst[dst[e]], 1);
  }
}

// two independent single-block scans; also folds nodeparams:
// block 0: deg -> rowptr,nextp + dis = rsqrt(deg+1)
// block 1: cnt -> srow,nexts   + invcnt = 1/max(cnt,1)
__global__ void scan2_kernel(const int* __restrict__ a0, int* __restrict__ r0, int* __restrict__ n0,
                             float* __restrict__ aux0,
                             const int* __restrict__ a1, int* __restrict__ r1, int* __restrict__ n1,
                             float* __restrict__ aux1)
{
  const int* a = blockIdx.x ? a1 : a0;
  int* r = blockIdx.x ? r1 : r0;
  int* n = blockIdx.x ? n1 : n0;
  float* aux = blockIdx.x ? aux1 : aux0;
  const int T = 256;
  int tid = threadIdx.x;
  int chunk = (NN + T - 1) / T;
  int begin = tid*chunk, end = begin + chunk; if (end > NN) end = NN; if (begin > NN) begin = NN;
  int s = 0;
  for (int i = begin; i < end; i++) s += a[i];
  __shared__ int ps[T];
  ps[tid] = s; __syncthreads();
  for (int off = 1; off < T; off <<= 1) {
    int v = 0;
    if (tid >= off) v = ps[tid - off];
    __syncthreads();
    if (tid >= off) ps[tid] += v;
    __syncthreads();
  }
  int base = (tid == 0) ? 0 : ps[tid-1];
  for (int i = begin; i < end; i++) {
    r[i] = base; n[i] = base; base += a[i];
    aux[i] = blockIdx.x ? (1.0f / fmaxf((float)a[i], 1.0f)) : rsqrtf((float)a[i] + 1.0f);
  }
  if (tid == T-1) r[NN] = base;
}

// fused CSR fill + src-sort fill (one pass over the edge list)
__global__ void fill_both_kernel(const int* __restrict__ src, const int* __restrict__ dst,
                                 int* __restrict__ nextp, int* __restrict__ csr_src,
                                 int* __restrict__ nexts, int* __restrict__ eperm,
                                 int* __restrict__ srcsorted)
{
  int e = blockIdx.x*blockDim.x + threadIdx.x;
  if (e < NE) {
    int s = src[e];
    int pos = atomicAdd(&nextp[dst[e]], 1);
    csr_src[pos] = s;
    int ps = atomicAdd(&nexts[s], 1);
    eperm[ps] = e;
    srcsorted[ps] = s;
  }
}

// ---------------------------------------------------------------------------
// BN fold: reduce 64-slice partials -> scale/shift; fold into conv2 weight.
// grid = 16 blocks; block b handles k in [b*8, b*8+8). cvec pre-zeroed.
// ---------------------------------------------------------------------------
__global__ __launch_bounds__(256)
void bn_fold_kernel(const float* __restrict__ slsums, const float* __restrict__ g,
                    const float* __restrict__ b, const float* __restrict__ W2,
                    short* __restrict__ Wfh, short* __restrict__ Wfl,
                    float* __restrict__ cvec)
{
  __shared__ float scale_s[DD], shift_s[DD];
  int tid = threadIdx.x;
  if (tid < DD) {
    float s = 0.f, q = 0.f;
    for (int sl = 0; sl < NSLICE; sl++) {
      s += slsums[sl*256 + tid];
      q += slsums[sl*256 + 128 + tid];
    }
    float m = s / (float)NN;
    float var = q / (float)NN - m*m;
    float is = rsqrtf(var + LN_EPS);
    float sc = is * g[tid];
    scale_s[tid] = sc;
    shift_s[tid] = b[tid] - m * sc;
  }
  __syncthreads();
  int col = tid & 127, kh = tid >> 7;   // kh = 0..1
  float cpart = 0.f;
  #pragma unroll
  for (int kk = 0; kk < 4; kk++) {
    int k = blockIdx.x*8 + kh*4 + kk;
    float w = W2[k*DD + col];
    short2 t = f2bf2v(w * scale_s[k]);
    size_t o = ((size_t)(k >> 3)*128 + col)*8 + (k & 7);
    Wfh[o] = t.x; Wfl[o] = t.y;
    cpart += shift_s[k] * w;
  }
  atomicAdd(&cvec[col], cpart);
}

// ---------------------------------------------------------------------------
extern "C" void kernel_launch(void* const* d_in, const int* in_sizes, int n_in,
                              void* d_out, int out_size, void* d_ws, size_t ws_size,
                              hipStream_t stream)
{
  const float* node_feat = (const float*)d_in[0];
  const float* edge_feat = (const float*)d_in[1];
  const int*   edge_index = (const int*)d_in[2];
  const int* src = edge_index;
  const int* dst = edge_index + NE;

  const float* enW1 = (const float*)d_in[3];  const float* enb1 = (const float*)d_in[4];
  const float* enW2 = (const float*)d_in[5];  const float* enb2 = (const float*)d_in[6];
  const float* enW3 = (const float*)d_in[7];  const float* enb3 = (const float*)d_in[8];
  const float* enlg = (const float*)d_in[9];  const float* enlb = (const float*)d_in[10];

  const float* eeW1 = (const float*)d_in[11]; const float* eeb1 = (const float*)d_in[12];
  const float* eeW2 = (const float*)d_in[13]; const float* eeb2 = (const float*)d_in[14];
  const float* eeW3 = (const float*)d_in[15]; const float* eeb3 = (const float*)d_in[16];
  const float* eelg = (const float*)d_in[17]; const float* eelb = (const float*)d_in[18];

  const float* procW = (const float*)d_in[19];
  const float* procB = (const float*)d_in[20];
  const float* bnG   = (const float*)d_in[21];
  const float* bnB   = (const float*)d_in[22];

  const float* dW1 = (const float*)d_in[23]; const float* db1 = (const float*)d_in[24];
  const float* dW2 = (const float*)d_in[25]; const float* db2 = (const float*)d_in[26];
  const float* dW3 = (const float*)d_in[27]; const float* db3 = (const float*)d_in[28];
  const float* dlg = (const float*)d_in[29]; const float* dlb = (const float*)d_in[30];

  char* ws = (char*)d_ws;
  size_t off = 0;
  auto alloc = [&](size_t bytes) -> void* {
    void* p = ws + off;
    off = (off + bytes + 255) & ~(size_t)255;
    return p;
  };
  float* hn     = (float*)alloc((size_t)NN*DD*4);
  unsigned short* hbf = (unsigned short*)alloc((size_t)NN*DD*2);  // bf16 gather table
  unsigned short* ybf = (unsigned short*)alloc((size_t)NN*DD*2);  // bf16 y (BN input)
  float* dis    = (float*)alloc(NN*4);
  float* invcnt = (float*)alloc(NN*4);
  float* bnsl5  = (float*)alloc((size_t)5*SLSTRIDE*4);  // 5 x [64-slice s/q | cvec]
  int* deg    = (int*)alloc(NN*4);
  int* cnt    = (int*)alloc(NN*4);
  int* rowptr = (int*)alloc((NN+1)*4);
  int* nextp  = (int*)alloc(NN*4);
  int* srow   = (int*)alloc((NN+1)*4);
  int* nexts  = (int*)alloc(NN*4);
  int* csr    = (int*)alloc((size_t)NE*4);
  int* eperm  = (int*)alloc((size_t)NE*4);
  int* srcsorted = (int*)alloc((size_t)NE*4);
  auto allocW = [&](int kp) { return (short*)alloc((size_t)kp*128*2); };
  short *pN1h=allocW(32),  *pN1l=allocW(32);
  short *pN2h=allocW(128), *pN2l=allocW(128);
  short *pN3h=allocW(128), *pN3l=allocW(128);
  short *pE1h=allocW(32),  *pE1l=allocW(32);
  short *pE2h=allocW(128), *pE2l=allocW(128);
  short *pE3h=allocW(128), *pE3l=allocW(128);
  short *pD1h=allocW(128), *pD1l=allocW(128);
  short *pD2h=allocW(128), *pD2l=allocW(128);
  short *pD3h=allocW(128), *pD3l=allocW(128);
  short *pP0h[5], *pP0l[5];
  for (int s = 0; s < 5; s++) { pP0h[s]=allocW(128); pP0l[s]=allocW(128); }
  short *pWfh=allocW(128), *pWfl=allocW(128);

  (void)hipMemsetAsync(deg, 0, NN*4, stream);
  (void)hipMemsetAsync(cnt, 0, NN*4, stream);
  (void)hipMemsetAsync(bnsl5, 0, (size_t)5*SLSTRIDE*4, stream);

  // pack static weights: 12 K=128 mats in one launch + 1 small 2D launch
  PackArgs pa;
  const float* s128[NPACK] = { enW2, enW3, eeW2, eeW3, dW1, dW2, dW3,
                               procW + 0*(size_t)DD*DD*2, procW + 1*(size_t)DD*DD*2,
                               procW + 2*(size_t)DD*DD*2, procW + 3*(size_t)DD*DD*2,
                               procW + 4*(size_t)DD*DD*2 };
  short* d128h[NPACK] = { pN2h, pN3h, pE2h, pE3h, pD1h, pD2h, pD3h,
                          pP0h[0], pP0h[1], pP0h[2], pP0h[3], pP0h[4] };
  short* d128l[NPACK] = { pN2l, pN3l, pE2l, pE3l, pD1l, pD2l, pD3l,
                          pP0l[0], pP0l[1], pP0l[2], pP0l[3], pP0l[4] };
  for (int m = 0; m < NPACK; m++) { pa.src[m]=s128[m]; pa.dh[m]=d128h[m]; pa.dl[m]=d128l[m]; }
  pack_many_kernel<<<dim3(64, NPACK), 256, 0, stream>>>(pa);
  pack_small_kernel<<<dim3(16, 2), 256, 0, stream>>>(enW1, pN1h, pN1l, eeW1, eeb1, pE1h);

  // graph setup
  count_kernel<<<(NE+255)/256, 256, 0, stream>>>(src, dst, cnt, deg);
  scan2_kernel<<<2, 256, 0, stream>>>(deg, rowptr, nextp, dis, cnt, srow, nexts, invcnt);
  fill_both_kernel<<<(NE+255)/256, 256, 0, stream>>>(src, dst, nextp, csr, nexts, eperm, srcsorted);

  const int GN  = (NN + 127) / 128;  // 391
  const int GE  = NE / 128;          // 6250
  const int GG  = (NN + 63) / 64;    // 782
  const int GA  = NN / 4;            // 12500 (exact; agg has no bounds check)

  // encoders: node MLP writes hn, edge MLP atomically adds scatter-mean into hn
  mlp_mfma_kernel<19, false><<<GN, 256, 0, stream>>>(node_feat, NN,
      pN1h, pN1l, enb1, pN2h, pN2l, enb2, pN3h, pN3l, enb3, enlg, enlb, hn,
      nullptr, nullptr, nullptr);
  mlp_mfma_kernel<4, true><<<GE, 256, 0, stream>>>(edge_feat, NE,
      pE1h, pE1l, eeb1, pE2h, pE2l, eeb2, pE3h, pE3l, eeb3, eelg, eelb, hn,
      srcsorted, eperm, invcnt);

  // processor: 5 residual (conv -> leaky -> BN -> conv) steps
  for (int s = 0; s < 5; s++) {
    const float* Wc2 = procW + (size_t)(s*2+1)*DD*DD;
    const float* b0  = procB + (size_t)(s*2+0)*DD;
    const float* b1p = procB + (size_t)(s*2+1)*DD;
    float* sl   = bnsl5 + (size_t)s*SLSTRIDE;
    float* cvec = sl + NSLICE*256;

    gemm_mfma_kernel<<<GG, 256, 0, stream>>>(hn, pP0h[s], pP0l[s], nullptr, dis, hbf, NN);
    gcn_agg_kernel<<<GA, 256, 0, stream>>>((const unsigned*)hbf, rowptr, csr, dis,
                                           b0, nullptr, nullptr, (unsigned*)ybf, sl, 0);
    bn_fold_kernel<<<16, 256, 0, stream>>>(sl, bnG + s*DD, bnB + s*DD, Wc2, pWfh, pWfl, cvec);
    gemm_bf_mfma_kernel<<<GG, 256, 0, stream>>>(ybf, pWfh, pWfl, cvec, dis, hbf, NN);
    gcn_agg_kernel<<<GA, 256, 0, stream>>>((const unsigned*)hbf, rowptr, csr, dis,
                                           b1p, hn, hn, nullptr, nullptr, 1);
  }

  // decoder -> d_out (fp32)
  mlp_mfma_kernel<128, false><<<GN, 256, 0, stream>>>(hn, NN,
      pD1h, pD1l, db1, pD2h, pD2l, db2, pD3h, pD3l, db3, dlg, dlb, (float*)d_out,
      nullptr, nullptr, nullptr);
}

// Round 8
// 1229.666 us; speedup vs baseline: 1.2364x; 1.0160x over previous
//
#include <hip/hip_runtime.h>

#define NN 50000
#define NE 800000
#define DD 128
#define LN_EPS 1e-5f
#define NSLICE 64
#define SLSTRIDE (NSLICE*256 + DD)   // per-step: 64 slices x [s(128)|q(128)] + cvec(128)

typedef __attribute__((ext_vector_type(8))) short v8s;    // 8 bf16
typedef __attribute__((ext_vector_type(4))) unsigned v4u; // same 16B as v8s
typedef __attribute__((ext_vector_type(4))) float f32x4;  // MFMA acc
typedef __attribute__((ext_vector_type(2))) float f32x2;  // packed-f32 pair

union CvtHL { v4u u; v8s s; };

__device__ __forceinline__ float leakyf(float x){ return x > 0.f ? x : 0.05f*x; }
__device__ __forceinline__ short f2bf(float f){
  unsigned u = __float_as_uint(f);
  u = (u + 0x7fffu + ((u >> 16) & 1u)) >> 16;   // RNE
  return (short)u;
}
__device__ __forceinline__ float bf2f(unsigned short h){
  return __uint_as_float(((unsigned)h) << 16);
}
// HW RNE pack: low16 = bf16(a), high16 = bf16(b). 1 inst for 2 values.
__device__ __forceinline__ unsigned cvt_pk_bf16(float a, float b){
  unsigned r;
  asm("v_cvt_pk_bf16_f32 %0, %1, %2" : "=v"(r) : "v"(a), "v"(b));
  return r;
}
// packed f32 math (CDNA VOP3P): 2 floats / instruction
__device__ __forceinline__ f32x2 pk_add(f32x2 a, f32x2 b){
  f32x2 r; asm("v_pk_add_f32 %0, %1, %2" : "=v"(r) : "v"(a), "v"(b)); return r;
}
__device__ __forceinline__ f32x2 pk_mul(f32x2 a, f32x2 b){
  f32x2 r; asm("v_pk_mul_f32 %0, %1, %2" : "=v"(r) : "v"(a), "v"(b)); return r;
}
// [hi16(u0) | hi16(u1)<<16] in one v_perm_b32
__device__ __forceinline__ unsigned pack_hi16(unsigned u0, unsigned u1){
  return __builtin_amdgcn_perm(u1, u0, 0x07060302u);
}
// split fp32 -> {hi, lo}: hi = truncated top-16 (cheap), lo = RNE(residual).
__device__ __forceinline__ short2 f2bf2v(float v){
  unsigned u = __float_as_uint(v);
  short hi = (short)(u >> 16);
  float lo = v - __uint_as_float(u & 0xffff0000u);
  return make_short2(hi, f2bf(lo));
}

// ---------------------------------------------------------------------------
// Weight packing. Layout: [(k>>3)*128+n][k&7] hi/lo bf16 planes.
// pack_small: y=0 node-encoder W1 (K=19 padded to 32) -> hi/lo planes;
//             y=1 edge-encoder W1+b1 folded single plane (see below).
// ---------------------------------------------------------------------------
__global__ void pack_small_kernel(const float* __restrict__ nW1,
                                  short* __restrict__ nWh, short* __restrict__ nWl,
                                  const float* __restrict__ eW1, const float* __restrict__ eb1,
                                  short* __restrict__ eWp)
{
  int idx = blockIdx.x*256 + threadIdx.x;   // 0..4095
  int k = idx >> 7, n = idx & 127;
  size_t o = ((size_t)(k >> 3)*128 + n)*8 + (k & 7);
  if (blockIdx.y == 0) {
    float v = (k < 19) ? nW1[k*128 + n] : 0.f;
    short2 t = f2bf2v(v);
    nWh[o] = t.x; nWl[o] = t.y;
  } else {
    // rows 0-3: hi(W1) (pairs A=xh); 4-7: lo(W1) (A=xh); 8-11: hi(W1) (A=xl);
    // 12: hi(b1), 13: lo(b1) (A=1.0); rest 0. One MFMA = xh@Wh+xh@Wl+xl@Wh+b1.
    short v = 0;
    if (k < 4)        v = f2bf2v(eW1[k*128 + n]).x;
    else if (k < 8)   v = f2bf2v(eW1[(k-4)*128 + n]).y;
    else if (k < 12)  v = f2bf2v(eW1[(k-8)*128 + n]).x;
    else if (k == 12) v = f2bf2v(eb1[n]).x;
    else if (k == 13) v = f2bf2v(eb1[n]).y;
    eWp[o] = v;
  }
}

#define NPACK 12
struct PackArgs { const float* src[NPACK]; short* dh[NPACK]; short* dl[NPACK]; };

// all-K=128 batch pack: grid (64, NPACK)
__global__ void pack_many_kernel(PackArgs pa)
{
  int m = blockIdx.y;
  int idx = blockIdx.x*256 + threadIdx.x;   // 0..16383
  int k = idx >> 7, n = idx & 127;
  float v = pa.src[m][k*128 + n];
  short2 t = f2bf2v(v);
  size_t o = ((size_t)(k >> 3)*128 + n)*8 + (k & 7);
  pa.dh[m][o] = t.x; pa.dl[m][o] = t.y;
}

// full split-split product (A has hi+lo)
#define MFMA3(ah, al, bh, bl, ac) \
  ac = __builtin_amdgcn_mfma_f32_16x16x32_bf16(al, bh, ac, 0,0,0); \
  ac = __builtin_amdgcn_mfma_f32_16x16x32_bf16(ah, bl, ac, 0,0,0); \
  ac = __builtin_amdgcn_mfma_f32_16x16x32_bf16(ah, bh, ac, 0,0,0);

// A exact-bf16 (no lo plane): 2 MFMAs
#define MFMA2(ah, bh, bl, ac) \
  ac = __builtin_amdgcn_mfma_f32_16x16x32_bf16(ah, bl, ac, 0,0,0); \
  ac = __builtin_amdgcn_mfma_f32_16x16x32_bf16(ah, bh, ac, 0,0,0);

// 8 fp32 -> hi-plane (v_perm pack) + lo-plane (cvt_pk RNE)
#define SPLIT8(f0, f1, h, l) { \
  unsigned u0=__float_as_uint(f0.x), u1=__float_as_uint(f0.y), u2=__float_as_uint(f0.z), u3=__float_as_uint(f0.w); \
  unsigned u4=__float_as_uint(f1.x), u5=__float_as_uint(f1.y), u6=__float_as_uint(f1.z), u7=__float_as_uint(f1.w); \
  CvtHL ch_, cl_; \
  ch_.u = (v4u){ pack_hi16(u0,u1), pack_hi16(u2,u3), pack_hi16(u4,u5), pack_hi16(u6,u7) }; \
  cl_.u = (v4u){ \
    cvt_pk_bf16(f0.x-__uint_as_float(u0&0xffff0000u), f0.y-__uint_as_float(u1&0xffff0000u)), \
    cvt_pk_bf16(f0.z-__uint_as_float(u2&0xffff0000u), f0.w-__uint_as_float(u3&0xffff0000u)), \
    cvt_pk_bf16(f1.x-__uint_as_float(u4&0xffff0000u), f1.y-__uint_as_float(u5&0xffff0000u)), \
    cvt_pk_bf16(f1.z-__uint_as_float(u6&0xffff0000u), f1.w-__uint_as_float(u7&0xffff0000u)) }; \
  h = ch_.s; l = cl_.s; }

// bias + leaky + bf16-pack on paired acc halves. Bit-identical to the scalar
// version: x=acc+bv (pk_add), m=0.05*x (pk_mul), max, HW-RNE cvt.
#define EPI_PK(accv, bv2, DOBIAS, p01, p23) { \
  f32x2 x01 = (f32x2){(accv)[0], (accv)[1]}; \
  f32x2 x23 = (f32x2){(accv)[2], (accv)[3]}; \
  if (DOBIAS) { x01 = pk_add(x01, bv2); x23 = pk_add(x23, bv2); } \
  f32x2 m01 = pk_mul(x01, (f32x2)(0.05f)); \
  f32x2 m23 = pk_mul(x23, (f32x2)(0.05f)); \
  p01 = cvt_pk_bf16(fmaxf(x01.x, m01.x), fmaxf(x01.y, m01.y)); \
  p23 = cvt_pk_bf16(fmaxf(x23.x, m23.x), fmaxf(x23.y, m23.y)); }

// ---------------------------------------------------------------------------
// 3-layer MLP + LayerNorm. Layer-1 inputs and all weights hi/lo split;
// hidden activations single-bf16 (layers 2/3 use 2 MFMAs).
// SCATTER (edge): layer-1 uses the single-plane combined weight (1 MFMA/tile,
// bias folded into K); LN stats use a shared reduce-scatter butterfly;
// seg-reduce flushes are pre-scaled by invcnt[src] and land directly in hn
// (scatter-MEAN fused -> no esum buffer / memset / addmean pass).
// ---------------------------------------------------------------------------
template<int IN_W, bool SCATTER>
__global__ __launch_bounds__(256)
void mlp_mfma_kernel(const float* __restrict__ x, int nrows,
                     const short* __restrict__ W1h, const short* __restrict__ W1l,
                     const float* __restrict__ b1,
                     const short* __restrict__ W2h, const short* __restrict__ W2l,
                     const float* __restrict__ b2,
                     const short* __restrict__ W3h, const short* __restrict__ W3l,
                     const float* __restrict__ b3,
                     const float* __restrict__ g, const float* __restrict__ bb,
                     float* __restrict__ out,
                     const int* __restrict__ sidx,   // src-sorted src values
                     const int* __restrict__ eperm,  // sorted pos -> edge id
                     const float* __restrict__ invcnt) // 1/max(cnt,1) per node
{
  constexpr int L1K = (IN_W + 31) / 32;
  constexpr bool EDGE1 = (SCATTER && IN_W == 4);
  __shared__ __align__(16) short Hh[128*136];   // act plane; reused (stride 132) as bf16 seg buffer
  __shared__ float lnS[128][2], lnQ[128][2];
  __shared__ int sidx_s[128];
  __shared__ __align__(16) uint4 xstage[SCATTER ? 128 : 1];  // pre-split hi/lo packs

  const int tid  = threadIdx.x;
  const int lane = tid & 63, wave = tid >> 6;
  const int wr = wave >> 1, wc = wave & 1;
  const int quad = lane >> 4, low = lane & 15;
  const int row0 = blockIdx.x * 128;

  if (SCATTER) {
    // 128 parallel scattered gathers + hi/lo split -> LDS stage
    if (tid < 128) {
      int e = eperm[row0 + tid];           // NE % 128 == 0
      float4 f = ((const float4*)x)[e];
      unsigned u0=__float_as_uint(f.x), u1=__float_as_uint(f.y);
      unsigned u2=__float_as_uint(f.z), u3=__float_as_uint(f.w);
      uint4 st;
      st.x = pack_hi16(u0,u1);
      st.y = pack_hi16(u2,u3);
      st.z = cvt_pk_bf16(f.x-__uint_as_float(u0&0xffff0000u), f.y-__uint_as_float(u1&0xffff0000u));
      st.w = cvt_pk_bf16(f.z-__uint_as_float(u2&0xffff0000u), f.w-__uint_as_float(u3&0xffff0000u));
      xstage[tid] = st;
      sidx_s[tid] = sidx[row0 + tid];
    }
    __syncthreads();
  }

  f32x4 acc[4][4];

  // ---------------- layer 1 ----------------
  #pragma unroll
  for (int tm=0;tm<4;tm++)
    #pragma unroll
    for (int tn=0;tn<4;tn++) acc[tm][tn] = (f32x4)0.f;

  if constexpr (EDGE1) {
    // single-plane: K slots 0-7 = xh (pairs Wh,Wl rows), 8-11 = xl (pairs Wh),
    // 12-13 = 1.0 (pairs b1 hi/lo rows). One MFMA per tile.
    v8s ah[4], bh[4];
    #pragma unroll
    for (int tm=0;tm<4;tm++) {
      int lr = wr*64 + tm*16 + low;
      v8s h = (v8s)0;
      if (quad == 0) {
        uint4 st = xstage[lr];
        CvtHL c_; c_.u = (v4u){ st.x, st.y, st.x, st.y };
        h = c_.s;
      } else if (quad == 1) {
        uint4 st = xstage[lr];
        CvtHL c_; c_.u = (v4u){ st.z, st.w, 0x3F803F80u, 0u };
        h = c_.s;
      }
      ah[tm] = h;
    }
    #pragma unroll
    for (int tn=0;tn<4;tn++) {
      size_t o = ((size_t)quad*128 + wc*64 + tn*16 + low)*8;
      bh[tn] = *(const v8s*)(W1h + o);
    }
    #pragma unroll
    for (int tm=0;tm<4;tm++)
      #pragma unroll
      for (int tn=0;tn<4;tn++)
        acc[tm][tn] = __builtin_amdgcn_mfma_f32_16x16x32_bf16(ah[tm], bh[tn], acc[tm][tn], 0,0,0);
  } else {
    for (int ks = 0; ks < L1K; ks++) {
      v8s ah[4], al[4], bh[4], bl[4];
      #pragma unroll
      for (int tm=0;tm<4;tm++) {
        int lr = wr*64 + tm*16 + low;
        v8s h = (v8s)0, l = (v8s)0;
        if (IN_W % 32 == 0) {
          int r = row0 + lr;
          if (r < nrows) {
            const float* p = x + (size_t)r*IN_W + ks*32 + quad*8;
            float4 f0 = *(const float4*)p;
            float4 f1 = *(const float4*)(p + 4);
            SPLIT8(f0, f1, h, l);
          }
        } else {
          int r = row0 + lr;
          #pragma unroll
          for (int j=0;j<8;j++) {
            int k = ks*32 + quad*8 + j;
            if (k < IN_W && r < nrows) {
              short2 t = f2bf2v(x[(size_t)r*IN_W + k]);
              h[j] = t.x; l[j] = t.y;
            }
          }
        }
        ah[tm] = h; al[tm] = l;
      }
      #pragma unroll
      for (int tn=0;tn<4;tn++) {
        size_t o = ((size_t)(ks*4+quad)*128 + wc*64 + tn*16 + low)*8;
        bh[tn] = *(const v8s*)(W1h + o);
        bl[tn] = *(const v8s*)(W1l + o);
      }
      #pragma unroll
      for (int tm=0;tm<4;tm++)
        #pragma unroll
        for (int tn=0;tn<4;tn++) { MFMA3(ah[tm], al[tm], bh[tn], bl[tn], acc[tm][tn]); }
    }
  }
  #pragma unroll
  for (int tn=0;tn<4;tn++) {
    float bv = EDGE1 ? 0.f : b1[wc*64 + tn*16 + low];
    f32x2 bv2 = (f32x2)(bv);
    #pragma unroll
    for (int tm=0;tm<4;tm++) {
      unsigned p01, p23;
      EPI_PK(acc[tm][tn], bv2, !EDGE1, p01, p23);
      int base = (wr*64+tm*16+quad*4)*136 + wc*64+tn*16+low;
      Hh[base]     = (short)p01;
      Hh[base+136] = (short)(p01>>16);
      Hh[base+272] = (short)p23;
      Hh[base+408] = (short)(p23>>16);
    }
  }
  __syncthreads();

  // ---------------- layer 2 (bf16 A from LDS, 2 MFMAs) ----------------
  #pragma unroll
  for (int tm=0;tm<4;tm++)
    #pragma unroll
    for (int tn=0;tn<4;tn++) acc[tm][tn] = (f32x4)0.f;
  #pragma unroll
  for (int ks=0;ks<4;ks++) {
    v8s ah[4], bh[4], bl[4];
    #pragma unroll
    for (int tm=0;tm<4;tm++)
      ah[tm] = *(const v8s*)&Hh[(wr*64+tm*16+low)*136 + ks*32 + quad*8];
    #pragma unroll
    for (int tn=0;tn<4;tn++) {
      size_t o = ((size_t)(ks*4+quad)*128 + wc*64 + tn*16 + low)*8;
      bh[tn] = *(const v8s*)(W2h + o);
      bl[tn] = *(const v8s*)(W2l + o);
    }
    #pragma unroll
    for (int tm=0;tm<4;tm++)
      #pragma unroll
      for (int tn=0;tn<4;tn++) { MFMA2(ah[tm], bh[tn], bl[tn], acc[tm][tn]); }
  }
  __syncthreads();
  #pragma unroll
  for (int tn=0;tn<4;tn++) {
    float bv = b2[wc*64 + tn*16 + low];
    f32x2 bv2 = (f32x2)(bv);
    #pragma unroll
    for (int tm=0;tm<4;tm++) {
      unsigned p01, p23;
      EPI_PK(acc[tm][tn], bv2, true, p01, p23);
      int base = (wr*64+tm*16+quad*4)*136 + wc*64+tn*16+low;
      Hh[base]     = (short)p01;
      Hh[base+136] = (short)(p01>>16);
      Hh[base+272] = (short)p23;
      Hh[base+408] = (short)(p23>>16);
    }
  }
  __syncthreads();

  // ---------------- layer 3 (bf16 A from LDS, 2 MFMAs) ----------------
  #pragma unroll
  for (int tm=0;tm<4;tm++)
    #pragma unroll
    for (int tn=0;tn<4;tn++) acc[tm][tn] = (f32x4)0.f;
  #pragma unroll
  for (int ks=0;ks<4;ks++) {
    v8s ah[4], bh[4], bl[4];
    #pragma unroll
    for (int tm=0;tm<4;tm++)
      ah[tm] = *(const v8s*)&Hh[(wr*64+tm*16+low)*136 + ks*32 + quad*8];
    #pragma unroll
    for (int tn=0;tn<4;tn++) {
      size_t o = ((size_t)(ks*4+quad)*128 + wc*64 + tn*16 + low)*8;
      bh[tn] = *(const v8s*)(W3h + o);
      bl[tn] = *(const v8s*)(W3l + o);
    }
    #pragma unroll
    for (int tm=0;tm<4;tm++)
      #pragma unroll
      for (int tn=0;tn<4;tn++) { MFMA2(ah[tm], bh[tn], bl[tn], acc[tm][tn]); }
  }
  #pragma unroll
  for (int tn=0;tn<4;tn++) {
    float bv = b3[wc*64 + tn*16 + low];
    #pragma unroll
    for (int tm=0;tm<4;tm++)
      #pragma unroll
      for (int i=0;i<4;i++) acc[tm][tn][i] += bv;
  }

  // ---------------- fused LayerNorm ----------------
  // Reduce-scatter butterfly: all 16 (tm,i) row-reductions share one 4-step
  // butterfly (masks 1,2,4,8 — identical tree association, bit-identical).
  {
    float ct[16];
    #pragma unroll
    for (int tm=0;tm<4;tm++)
      #pragma unroll
      for (int i=0;i<4;i++)
        ct[tm*4+i] = acc[tm][0][i] + acc[tm][1][i] + acc[tm][2][i] + acc[tm][3][i];
    #pragma unroll
    for (int st=0; st<4; st++) {
      const int mm = 1 << st;
      const bool hbit = ((low >> st) & 1) != 0;
      #pragma unroll
      for (int p=0; p < (16>>st); p+=2) {
        float snd = hbit ? ct[p]   : ct[p+1];
        float kp  = hbit ? ct[p+1] : ct[p];
        ct[p>>1] = kp + __shfl_xor(snd, mm);
      }
    }
    { int r = wr*64 + (low>>2)*16 + quad*4 + (low&3); lnS[r][wc] = ct[0]; }
    #pragma unroll
    for (int tm=0;tm<4;tm++)
      #pragma unroll
      for (int i=0;i<4;i++)
        ct[tm*4+i] = acc[tm][0][i]*acc[tm][0][i] + acc[tm][1][i]*acc[tm][1][i]
                   + acc[tm][2][i]*acc[tm][2][i] + acc[tm][3][i]*acc[tm][3][i];
    #pragma unroll
    for (int st=0; st<4; st++) {
      const int mm = 1 << st;
      const bool hbit = ((low >> st) & 1) != 0;
      #pragma unroll
      for (int p=0; p < (16>>st); p+=2) {
        float snd = hbit ? ct[p]   : ct[p+1];
        float kp  = hbit ? ct[p+1] : ct[p];
        ct[p>>1] = kp + __shfl_xor(snd, mm);
      }
    }
    { int r = wr*64 + (low>>2)*16 + quad*4 + (low&3); lnQ[r][wc] = ct[0]; }
  }
  __syncthreads();   // all layer-3 H reads done (act-plane reuse below is safe)

  float g4[4], bb4[4];
  #pragma unroll
  for (int tn=0;tn<4;tn++) { int c = wc*64+tn*16+low; g4[tn] = g[c]; bb4[tn] = bb[c]; }

  #pragma unroll
  for (int tm=0;tm<4;tm++)
    #pragma unroll
    for (int i=0;i<4;i++) {
      int r = wr*64 + tm*16 + quad*4 + i;
      float2 S2 = *(const float2*)&lnS[r][0];
      float2 Q2 = *(const float2*)&lnQ[r][0];
      float s = S2.x + S2.y;
      float q = Q2.x + Q2.y;
      float m = s * (1.f/128.f);
      float var = q * (1.f/128.f) - m*m;
      float rs = rsqrtf(var + LN_EPS);
      int gr = row0 + r;
      if (!SCATTER && gr >= nrows) continue;
      float v0 = (acc[tm][0][i] - m) * rs * g4[0] + bb4[0];
      float v1 = (acc[tm][1][i] - m) * rs * g4[1] + bb4[1];
      float v2 = (acc[tm][2][i] - m) * rs * g4[2] + bb4[2];
      float v3 = (acc[tm][3][i] - m) * rs * g4[3] + bb4[3];
      if (SCATTER) {
        unsigned p01 = cvt_pk_bf16(v0, v1), p23 = cvt_pk_bf16(v2, v3);
        int base = r*132 + wc*64 + low;
        Hh[base]    = (short)p01;      // bf16 stage for seg-reduce
        Hh[base+16] = (short)(p01>>16);
        Hh[base+32] = (short)p23;
        Hh[base+48] = (short)(p23>>16);
      } else {
        size_t ob = (size_t)gr*DD + wc*64 + low;
        out[ob]    = v0;
        out[ob+16] = v1;
        out[ob+32] = v2;
        out[ob+48] = v3;
      }
    }

  if (SCATTER) {
    __syncthreads();
    // dword-vectorized seg-reduce: wave g handles rows [g*32, g*32+32),
    // 64 col-pairs; flushes scaled by invcnt[cur] straight into hn.
    const unsigned* H32 = (const unsigned*)Hh;    // row stride 66 dwords
    int cp = tid & 63;
    int gI = tid >> 6;
    int rbeg = gI*32, rend = rbeg + 32;
    unsigned pv = H32[rbeg*66 + cp];
    float a0 = __uint_as_float(pv << 16), a1 = __uint_as_float(pv & 0xffff0000u);
    int cur = __builtin_amdgcn_readfirstlane(sidx_s[rbeg]);
    for (int r = rbeg + 1; r < rend; r++) {
      int sv = __builtin_amdgcn_readfirstlane(sidx_s[r]);   // wave-uniform scalar
      unsigned hv = H32[r*66 + cp];
      if (sv != cur) {
        float ic = invcnt[cur];
        atomicAdd(&out[(size_t)cur*DD + 2*cp],     a0*ic);
        atomicAdd(&out[(size_t)cur*DD + 2*cp + 1], a1*ic);
        a0 = __uint_as_float(hv << 16); a1 = __uint_as_float(hv & 0xffff0000u);
        cur = sv;
      } else {
        a0 += __uint_as_float(hv << 16); a1 += __uint_as_float(hv & 0xffff0000u);
      }
    }
    float ic = invcnt[cur];
    atomicAdd(&out[(size_t)cur*DD + 2*cp],     a0*ic);
    atomicAdd(&out[(size_t)cur*DD + 2*cp + 1], a1*ic);
  }
}

// ---------------------------------------------------------------------------
// outbf[r] = bf16((x[r] @ W + initv) * rowscale[r])  — fp32 input (split, 3 MFMA)
// ---------------------------------------------------------------------------
__global__ __launch_bounds__(256)
void gemm_mfma_kernel(const float* __restrict__ x,
                      const short* __restrict__ Wh, const short* __restrict__ Wl,
                      const float* __restrict__ initv, const float* __restrict__ rowscale,
                      unsigned short* __restrict__ outbf, int nrows)
{
  const int tid  = threadIdx.x;
  const int lane = tid & 63, wave = tid >> 6;
  const int wr = wave >> 1, wc = wave & 1;
  const int quad = lane >> 4, low = lane & 15;
  const int row0 = blockIdx.x * 64;

  f32x4 acc[2][4];
  #pragma unroll
  for (int tm=0;tm<2;tm++)
    #pragma unroll
    for (int tn=0;tn<4;tn++) acc[tm][tn] = (f32x4)0.f;

  #pragma unroll
  for (int ks=0;ks<4;ks++) {
    v8s ah[2], al[2], bh[4], bl[4];
    #pragma unroll
    for (int tm=0;tm<2;tm++) {
      int r = row0 + wr*32 + tm*16 + low;
      v8s h = (v8s)0, l = (v8s)0;
      if (r < nrows) {
        const float* p = x + (size_t)r*DD + ks*32 + quad*8;
        float4 f0 = *(const float4*)p;
        float4 f1 = *(const float4*)(p + 4);
        SPLIT8(f0, f1, h, l);
      }
      ah[tm] = h; al[tm] = l;
    }
    #pragma unroll
    for (int tn=0;tn<4;tn++) {
      size_t o = ((size_t)(ks*4+quad)*128 + wc*64 + tn*16 + low)*8;
      bh[tn] = *(const v8s*)(Wh + o);
      bl[tn] = *(const v8s*)(Wl + o);
    }
    #pragma unroll
    for (int tm=0;tm<2;tm++)
      #pragma unroll
      for (int tn=0;tn<4;tn++) { MFMA3(ah[tm], al[tm], bh[tn], bl[tn], acc[tm][tn]); }
  }

  float iv4[4];
  #pragma unroll
  for (int tn=0;tn<4;tn++) iv4[tn] = initv ? initv[wc*64 + tn*16 + low] : 0.f;

  #pragma unroll
  for (int tm=0;tm<2;tm++)
    #pragma unroll
    for (int i=0;i<4;i++) {
      int gr = row0 + wr*32 + tm*16 + quad*4 + i;
      if (gr >= nrows) continue;
      float sc = rowscale ? rowscale[gr] : 1.f;
      float v0 = (acc[tm][0][i] + iv4[0]) * sc;
      float v1 = (acc[tm][1][i] + iv4[1]) * sc;
      float v2 = (acc[tm][2][i] + iv4[2]) * sc;
      float v3 = (acc[tm][3][i] + iv4[3]) * sc;
      unsigned p01 = cvt_pk_bf16(v0, v1), p23 = cvt_pk_bf16(v2, v3);
      size_t base = (size_t)gr*DD + wc*64 + low;
      outbf[base]    = (unsigned short)p01;
      outbf[base+16] = (unsigned short)(p01>>16);
      outbf[base+32] = (unsigned short)p23;
      outbf[base+48] = (unsigned short)(p23>>16);
    }
}

// ---------------------------------------------------------------------------
// Same but bf16 input (exact, 2 MFMA, 16 B/lane A-loads) — conv2 on y.
// ---------------------------------------------------------------------------
__global__ __launch_bounds__(256)
void gemm_bf_mfma_kernel(const unsigned short* __restrict__ xb,
                         const short* __restrict__ Wh, const short* __restrict__ Wl,
                         const float* __restrict__ initv, const float* __restrict__ rowscale,
                         unsigned short* __restrict__ outbf, int nrows)
{
  const int tid  = threadIdx.x;
  const int lane = tid & 63, wave = tid >> 6;
  const int wr = wave >> 1, wc = wave & 1;
  const int quad = lane >> 4, low = lane & 15;
  const int row0 = blockIdx.x * 64;

  f32x4 acc[2][4];
  #pragma unroll
  for (int tm=0;tm<2;tm++)
    #pragma unroll
    for (int tn=0;tn<4;tn++) acc[tm][tn] = (f32x4)0.f;

  #pragma unroll
  for (int ks=0;ks<4;ks++) {
    v8s ah[2], bh[4], bl[4];
    #pragma unroll
    for (int tm=0;tm<2;tm++) {
      int r = row0 + wr*32 + tm*16 + low;
      ah[tm] = (r < nrows) ? *(const v8s*)(xb + (size_t)r*DD + ks*32 + quad*8) : (v8s)0;
    }
    #pragma unroll
    for (int tn=0;tn<4;tn++) {
      size_t o = ((size_t)(ks*4+quad)*128 + wc*64 + tn*16 + low)*8;
      bh[tn] = *(const v8s*)(Wh + o);
      bl[tn] = *(const v8s*)(Wl + o);
    }
    #pragma unroll
    for (int tm=0;tm<2;tm++)
      #pragma unroll
      for (int tn=0;tn<4;tn++) { MFMA2(ah[tm], bh[tn], bl[tn], acc[tm][tn]); }
  }

  float iv4[4];
  #pragma unroll
  for (int tn=0;tn<4;tn++) iv4[tn] = initv ? initv[wc*64 + tn*16 + low] : 0.f;

  #pragma unroll
  for (int tm=0;tm<2;tm++)
    #pragma unroll
    for (int i=0;i<4;i++) {
      int gr = row0 + wr*32 + tm*16 + quad*4 + i;
      if (gr >= nrows) continue;
      float sc = rowscale ? rowscale[gr] : 1.f;
      float v0 = (acc[tm][0][i] + iv4[0]) * sc;
      float v1 = (acc[tm][1][i] + iv4[1]) * sc;
      float v2 = (acc[tm][2][i] + iv4[2]) * sc;
      float v3 = (acc[tm][3][i] + iv4[3]) * sc;
      unsigned p01 = cvt_pk_bf16(v0, v1), p23 = cvt_pk_bf16(v2, v3);
      size_t base = (size_t)gr*DD + wc*64 + low;
      outbf[base]    = (unsigned short)p01;
      outbf[base+16] = (unsigned short)(p01>>16);
      outbf[base+32] = (unsigned short)p23;
      outbf[base+48] = (unsigned short)(p23>>16);
    }
}

// ---------------------------------------------------------------------------
// GCN aggregation, 2 NODES PER WAVE with interleaved gather bursts.
// Mechanism: the kernel is latency-bound (per-wave serial chain: rowptr ->
// scalar index block -> gathers ~1400cy vs ~150cy issue; occupancy cap 8
// waves/SIMD can't hide it). Two nodes per wave doubles loads-in-flight
// (32 in the main phase) and amortizes the startup chain.
// Per-node per-lane accumulation ORDER is unchanged (same 16/4/1 ladder)
// -> node outputs bit-identical to R7.
// mode 0: outb = bf16(leaky(agg)); fused BN stats (rounded values) via
//         block LDS reduce + 64-slice atomics.
// mode 1: outf = resid + agg (fp32)
// NN == gridDim.x*8 exactly -> no early return (block barrier safe).
// ---------------------------------------------------------------------------
#define GATH16(vv, jj) { \
  _Pragma("unroll") \
  for (int k=0;k<16;k++) vv[k] = hb[(size_t)csr_src[(jj)+k]*64 + lane]; }
#define CONS16(vv, ax, ay) { \
  _Pragma("unroll") \
  for (int k=0;k<16;k++) { \
    ax += bf2f((unsigned short)(vv[k] & 0xffff)); \
    ay += bf2f((unsigned short)(vv[k] >> 16)); } }
#define GATH4(vv, jj) { \
  _Pragma("unroll") \
  for (int k=0;k<4;k++) vv[k] = hb[(size_t)csr_src[(jj)+k]*64 + lane]; }
#define CONS4(vv, ax, ay) { \
  _Pragma("unroll") \
  for (int k=0;k<4;k++) { \
    ax += bf2f((unsigned short)(vv[k] & 0xffff)); \
    ay += bf2f((unsigned short)(vv[k] >> 16)); } }

__global__ __launch_bounds__(256)
void gcn_agg_kernel(const unsigned* __restrict__ hb, const int* __restrict__ rowptr,
                    const int* __restrict__ csr_src, const float* __restrict__ dis,
                    const float* __restrict__ bias, const float* __restrict__ resid,
                    float* __restrict__ outf, unsigned* __restrict__ outb,
                    float* __restrict__ slsums, int mode)
{
  __shared__ float red[256][4];
  const int wv = __builtin_amdgcn_readfirstlane(threadIdx.x >> 6);
  const int lane = threadIdx.x & 63;
  const int iA = blockIdx.x*8 + wv*2;   // NN % 8 == 0, grid = NN/8
  const int iB = iA + 1;
  const int begA = rowptr[iA], endA = rowptr[iA+1];
  const int begB = rowptr[iB], endB = rowptr[iB+1];
  unsigned hvA = hb[(size_t)iA*64 + lane];
  unsigned hvB = hb[(size_t)iB*64 + lane];
  float axA = bf2f((unsigned short)(hvA & 0xffff)), ayA = bf2f((unsigned short)(hvA >> 16));
  float axB = bf2f((unsigned short)(hvB & 0xffff)), ayB = bf2f((unsigned short)(hvB >> 16));
  int jA = begA, jB = begB;
  // interleaved 16-bursts: 32 loads in flight
  while (jA + 16 <= endA && jB + 16 <= endB) {
    unsigned vA[16], vB[16];
    GATH16(vA, jA); GATH16(vB, jB);
    CONS16(vA, axA, ayA); CONS16(vB, axB, ayB);
    jA += 16; jB += 16;
  }
  for (; jA + 16 <= endA; jA += 16) { unsigned v[16]; GATH16(v, jA); CONS16(v, axA, ayA); }
  for (; jB + 16 <= endB; jB += 16) { unsigned v[16]; GATH16(v, jB); CONS16(v, axB, ayB); }
  // interleaved 4-bursts
  while (jA + 4 <= endA && jB + 4 <= endB) {
    unsigned vA[4], vB[4];
    GATH4(vA, jA); GATH4(vB, jB);
    CONS4(vA, axA, ayA); CONS4(vB, axB, ayB);
    jA += 4; jB += 4;
  }
  for (; jA + 4 <= endA; jA += 4) { unsigned v[4]; GATH4(v, jA); CONS4(v, axA, ayA); }
  for (; jB + 4 <= endB; jB += 4) { unsigned v[4]; GATH4(v, jB); CONS4(v, axB, ayB); }
  for (; jA < endA; jA++) {
    unsigned v = hb[(size_t)csr_src[jA]*64 + lane];
    axA += bf2f((unsigned short)(v & 0xffff));
    ayA += bf2f((unsigned short)(v >> 16));
  }
  for (; jB < endB; jB++) {
    unsigned v = hb[(size_t)csr_src[jB]*64 + lane];
    axB += bf2f((unsigned short)(v & 0xffff));
    ayB += bf2f((unsigned short)(v >> 16));
  }
  float diA = dis[iA], diB = dis[iB];
  float2 bv = ((const float2*)bias)[lane];
  axA = axA*diA + bv.x; ayA = ayA*diA + bv.y;
  axB = axB*diB + bv.x; ayB = ayB*diB + bv.y;
  size_t oA = (size_t)iA*64 + lane, oB = (size_t)iB*64 + lane;
  if (mode == 0) {
    unsigned pkA = cvt_pk_bf16(leakyf(axA), leakyf(ayA));
    unsigned pkB = cvt_pk_bf16(leakyf(axB), leakyf(ayB));
    outb[oA] = pkA; outb[oB] = pkB;
    // fused BN stats on the rounded bf16 values (both nodes)
    float aA = bf2f((unsigned short)(pkA & 0xffff)), bA = bf2f((unsigned short)(pkA >> 16));
    float aB = bf2f((unsigned short)(pkB & 0xffff)), bB = bf2f((unsigned short)(pkB >> 16));
    red[threadIdx.x][0] = aA + aB;
    red[threadIdx.x][1] = bA + bB;
    red[threadIdx.x][2] = aA*aA + aB*aB;
    red[threadIdx.x][3] = bA*bA + bB*bB;
    __syncthreads();
    if (threadIdx.x < 64) {
      int l = threadIdx.x;
      float t0 = red[l][0] + red[64+l][0] + red[128+l][0] + red[192+l][0];
      float t1 = red[l][1] + red[64+l][1] + red[128+l][1] + red[192+l][1];
      float t2 = red[l][2] + red[64+l][2] + red[128+l][2] + red[192+l][2];
      float t3 = red[l][3] + red[64+l][3] + red[128+l][3] + red[192+l][3];
      float* S = slsums + (size_t)(blockIdx.x & (NSLICE-1))*256;
      atomicAdd(&S[2*l],       t0);
      atomicAdd(&S[2*l+1],     t1);
      atomicAdd(&S[128+2*l],   t2);
      atomicAdd(&S[128+2*l+1], t3);
    }
  } else {
    float2 rsA = ((const float2*)resid)[oA];
    float2 rsB = ((const float2*)resid)[oB];
    float2 rA; rA.x = rsA.x + axA; rA.y = rsA.y + ayA;
    float2 rB; rB.x = rsB.x + axB; rB.y = rsB.y + ayB;
    ((float2*)outf)[oA] = rA;
    ((float2*)outf)[oB] = rB;
  }
}

// ---------------------------------------------------------------------------
// Graph setup
// ---------------------------------------------------------------------------
__global__ void count_kernel(const int* __restrict__ src, const int* __restrict__ dst,
                             int* __restrict__ cnt_src, int* __restrict__ deg_dst)
{
  int e = blockIdx.x*blockDim.x + threadIdx.x;
  if (e < NE) {
    atomicAdd(&cnt_src[src[e]], 1);
    atomicAdd(&deg_dst[dst[e]], 1);
  }
}

// two independent single-block scans; also folds nodeparams:
// block 0: deg -> rowptr,nextp + dis = rsqrt(deg+1)
// block 1: cnt -> srow,nexts   + invcnt = 1/max(cnt,1)
__global__ void scan2_kernel(const int* __restrict__ a0, int* __restrict__ r0, int* __restrict__ n0,
                             float* __restrict__ aux0,
                             const int* __restrict__ a1, int* __restrict__ r1, int* __restrict__ n1,
                             float* __restrict__ aux1)
{
  const int* a = blockIdx.x ? a1 : a0;
  int* r = blockIdx.x ? r1 : r0;
  int* n = blockIdx.x ? n1 : n0;
  float* aux = blockIdx.x ? aux1 : aux0;
  const int T = 256;
  int tid = threadIdx.x;
  int chunk = (NN + T - 1) / T;
  int begin = tid*chunk, end = begin + chunk; if (end > NN) end = NN; if (begin > NN) begin = NN;
  int s = 0;
  for (int i = begin; i < end; i++) s += a[i];
  __shared__ int ps[T];
  ps[tid] = s; __syncthreads();
  for (int off = 1; off < T; off <<= 1) {
    int v = 0;
    if (tid >= off) v = ps[tid - off];
    __syncthreads();
    if (tid >= off) ps[tid] += v;
    __syncthreads();
  }
  int base = (tid == 0) ? 0 : ps[tid-1];
  for (int i = begin; i < end; i++) {
    r[i] = base; n[i] = base; base += a[i];
    aux[i] = blockIdx.x ? (1.0f / fmaxf((float)a[i], 1.0f)) : rsqrtf((float)a[i] + 1.0f);
  }
  if (tid == T-1) r[NN] = base;
}

// fused CSR fill + src-sort fill (one pass over the edge list)
__global__ void fill_both_kernel(const int* __restrict__ src, const int* __restrict__ dst,
                                 int* __restrict__ nextp, int* __restrict__ csr_src,
                                 int* __restrict__ nexts, int* __restrict__ eperm,
                                 int* __restrict__ srcsorted)
{
  int e = blockIdx.x*blockDim.x + threadIdx.x;
  if (e < NE) {
    int s = src[e];
    int pos = atomicAdd(&nextp[dst[e]], 1);
    csr_src[pos] = s;
    int ps = atomicAdd(&nexts[s], 1);
    eperm[ps] = e;
    srcsorted[ps] = s;
  }
}

// ---------------------------------------------------------------------------
// BN fold: reduce 64-slice partials -> scale/shift; fold into conv2 weight.
// grid = 16 blocks; block b handles k in [b*8, b*8+8). cvec pre-zeroed.
// ---------------------------------------------------------------------------
__global__ __launch_bounds__(256)
void bn_fold_kernel(const float* __restrict__ slsums, const float* __restrict__ g,
                    const float* __restrict__ b, const float* __restrict__ W2,
                    short* __restrict__ Wfh, short* __restrict__ Wfl,
                    float* __restrict__ cvec)
{
  __shared__ float scale_s[DD], shift_s[DD];
  int tid = threadIdx.x;
  if (tid < DD) {
    float s = 0.f, q = 0.f;
    for (int sl = 0; sl < NSLICE; sl++) {
      s += slsums[sl*256 + tid];
      q += slsums[sl*256 + 128 + tid];
    }
    float m = s / (float)NN;
    float var = q / (float)NN - m*m;
    float is = rsqrtf(var + LN_EPS);
    float sc = is * g[tid];
    scale_s[tid] = sc;
    shift_s[tid] = b[tid] - m * sc;
  }
  __syncthreads();
  int col = tid & 127, kh = tid >> 7;   // kh = 0..1
  float cpart = 0.f;
  #pragma unroll
  for (int kk = 0; kk < 4; kk++) {
    int k = blockIdx.x*8 + kh*4 + kk;
    float w = W2[k*DD + col];
    short2 t = f2bf2v(w * scale_s[k]);
    size_t o = ((size_t)(k >> 3)*128 + col)*8 + (k & 7);
    Wfh[o] = t.x; Wfl[o] = t.y;
    cpart += shift_s[k] * w;
  }
  atomicAdd(&cvec[col], cpart);
}

// ---------------------------------------------------------------------------
extern "C" void kernel_launch(void* const* d_in, const int* in_sizes, int n_in,
                              void* d_out, int out_size, void* d_ws, size_t ws_size,
                              hipStream_t stream)
{
  const float* node_feat = (const float*)d_in[0];
  const float* edge_feat = (const float*)d_in[1];
  const int*   edge_index = (const int*)d_in[2];
  const int* src = edge_index;
  const int* dst = edge_index + NE;

  const float* enW1 = (const float*)d_in[3];  const float* enb1 = (const float*)d_in[4];
  const float* enW2 = (const float*)d_in[5];  const float* enb2 = (const float*)d_in[6];
  const float* enW3 = (const float*)d_in[7];  const float* enb3 = (const float*)d_in[8];
  const float* enlg = (const float*)d_in[9];  const float* enlb = (const float*)d_in[10];

  const float* eeW1 = (const float*)d_in[11]; const float* eeb1 = (const float*)d_in[12];
  const float* eeW2 = (const float*)d_in[13]; const float* eeb2 = (const float*)d_in[14];
  const float* eeW3 = (const float*)d_in[15]; const float* eeb3 = (const float*)d_in[16];
  const float* eelg = (const float*)d_in[17]; const float* eelb = (const float*)d_in[18];

  const float* procW = (const float*)d_in[19];
  const float* procB = (const float*)d_in[20];
  const float* bnG   = (const float*)d_in[21];
  const float* bnB   = (const float*)d_in[22];

  const float* dW1 = (const float*)d_in[23]; const float* db1 = (const float*)d_in[24];
  const float* dW2 = (const float*)d_in[25]; const float* db2 = (const float*)d_in[26];
  const float* dW3 = (const float*)d_in[27]; const float* db3 = (const float*)d_in[28];
  const float* dlg = (const float*)d_in[29]; const float* dlb = (const float*)d_in[30];

  char* ws = (char*)d_ws;
  size_t off = 0;
  auto alloc = [&](size_t bytes) -> void* {
    void* p = ws + off;
    off = (off + bytes + 255) & ~(size_t)255;
    return p;
  };
  float* hn     = (float*)alloc((size_t)NN*DD*4);
  unsigned short* hbf = (unsigned short*)alloc((size_t)NN*DD*2);  // bf16 gather table
  unsigned short* ybf = (unsigned short*)alloc((size_t)NN*DD*2);  // bf16 y (BN input)
  float* dis    = (float*)alloc(NN*4);
  float* invcnt = (float*)alloc(NN*4);
  float* bnsl5  = (float*)alloc((size_t)5*SLSTRIDE*4);  // 5 x [64-slice s/q | cvec]
  int* deg    = (int*)alloc(NN*4);
  int* cnt    = (int*)alloc(NN*4);
  int* rowptr = (int*)alloc((NN+1)*4);
  int* nextp  = (int*)alloc(NN*4);
  int* srow   = (int*)alloc((NN+1)*4);
  int* nexts  = (int*)alloc(NN*4);
  int* csr    = (int*)alloc((size_t)NE*4);
  int* eperm  = (int*)alloc((size_t)NE*4);
  int* srcsorted = (int*)alloc((size_t)NE*4);
  auto allocW = [&](int kp) { return (short*)alloc((size_t)kp*128*2); };
  short *pN1h=allocW(32),  *pN1l=allocW(32);
  short *pN2h=allocW(128), *pN2l=allocW(128);
  short *pN3h=allocW(128), *pN3l=allocW(128);
  short *pE1h=allocW(32),  *pE1l=allocW(32);
  short *pE2h=allocW(128), *pE2l=allocW(128);
  short *pE3h=allocW(128), *pE3l=allocW(128);
  short *pD1h=allocW(128), *pD1l=allocW(128);
  short *pD2h=allocW(128), *pD2l=allocW(128);
  short *pD3h=allocW(128), *pD3l=allocW(128);
  short *pP0h[5], *pP0l[5];
  for (int s = 0; s < 5; s++) { pP0h[s]=allocW(128); pP0l[s]=allocW(128); }
  short *pWfh=allocW(128), *pWfl=allocW(128);

  (void)hipMemsetAsync(deg, 0, NN*4, stream);
  (void)hipMemsetAsync(cnt, 0, NN*4, stream);
  (void)hipMemsetAsync(bnsl5, 0, (size_t)5*SLSTRIDE*4, stream);

  // pack static weights: 12 K=128 mats in one launch + 1 small 2D launch
  PackArgs pa;
  const float* s128[NPACK] = { enW2, enW3, eeW2, eeW3, dW1, dW2, dW3,
                               procW + 0*(size_t)DD*DD*2, procW + 1*(size_t)DD*DD*2,
                               procW + 2*(size_t)DD*DD*2, procW + 3*(size_t)DD*DD*2,
                               procW + 4*(size_t)DD*DD*2 };
  short* d128h[NPACK] = { pN2h, pN3h, pE2h, pE3h, pD1h, pD2h, pD3h,
                          pP0h[0], pP0h[1], pP0h[2], pP0h[3], pP0h[4] };
  short* d128l[NPACK] = { pN2l, pN3l, pE2l, pE3l, pD1l, pD2l, pD3l,
                          pP0l[0], pP0l[1], pP0l[2], pP0l[3], pP0l[4] };
  for (int m = 0; m < NPACK; m++) { pa.src[m]=s128[m]; pa.dh[m]=d128h[m]; pa.dl[m]=d128l[m]; }
  pack_many_kernel<<<dim3(64, NPACK), 256, 0, stream>>>(pa);
  pack_small_kernel<<<dim3(16, 2), 256, 0, stream>>>(enW1, pN1h, pN1l, eeW1, eeb1, pE1h);

  // graph setup
  count_kernel<<<(NE+255)/256, 256, 0, stream>>>(src, dst, cnt, deg);
  scan2_kernel<<<2, 256, 0, stream>>>(deg, rowptr, nextp, dis, cnt, srow, nexts, invcnt);
  fill_both_kernel<<<(NE+255)/256, 256, 0, stream>>>(src, dst, nextp, csr, nexts, eperm, srcsorted);

  const int GN  = (NN + 127) / 128;  // 391
  const int GE  = NE / 128;          // 6250
  const int GG  = (NN + 63) / 64;    // 782
  const int GA  = NN / 8;            // 6250 (2 nodes/wave; no bounds check)

  // encoders: node MLP writes hn, edge MLP atomically adds scatter-mean into hn
  mlp_mfma_kernel<19, false><<<GN, 256, 0, stream>>>(node_feat, NN,
      pN1h, pN1l, enb1, pN2h, pN2l, enb2, pN3h, pN3l, enb3, enlg, enlb, hn,
      nullptr, nullptr, nullptr);
  mlp_mfma_kernel<4, true><<<GE, 256, 0, stream>>>(edge_feat, NE,
      pE1h, pE1l, eeb1, pE2h, pE2l, eeb2, pE3h, pE3l, eeb3, eelg, eelb, hn,
      srcsorted, eperm, invcnt);

  // processor: 5 residual (conv -> leaky -> BN -> conv) steps
  for (int s = 0; s < 5; s++) {
    const float* Wc2 = procW + (size_t)(s*2+1)*DD*DD;
    const float* b0  = procB + (size_t)(s*2+0)*DD;
    const float* b1p = procB + (size_t)(s*2+1)*DD;
    float* sl   = bnsl5 + (size_t)s*SLSTRIDE;
    float* cvec = sl + NSLICE*256;

    gemm_mfma_kernel<<<GG, 256, 0, stream>>>(hn, pP0h[s], pP0l[s], nullptr, dis, hbf, NN);
    gcn_agg_kernel<<<GA, 256, 0, stream>>>((const unsigned*)hbf, rowptr, csr, dis,
                                           b0, nullptr, nullptr, (unsigned*)ybf, sl, 0);
    bn_fold_kernel<<<16, 256, 0, stream>>>(sl, bnG + s*DD, bnB + s*DD, Wc2, pWfh, pWfl, cvec);
    gemm_bf_mfma_kernel<<<GG, 256, 0, stream>>>(ybf, pWfh, pWfl, cvec, dis, hbf, NN);
    gcn_agg_kernel<<<GA, 256, 0, stream>>>((const unsigned*)hbf, rowptr, csr, dis,
                                           b1p, hn, hn, nullptr, nullptr, 1);
  }

  // decoder -> d_out (fp32)
  mlp_mfma_kernel<128, false><<<GN, 256, 0, stream>>>(hn, NN,
      pD1h, pD1l, db1, pD2h, pD2l, db2, pD3h, pD3l, db3, dlg, dlb, (float*)d_out,
      nullptr, nullptr, nullptr);
}